// Round 16
// baseline (126.119 us; speedup 1.0000x reference)
//
#include <hip/hip_runtime.h>

#define D 512
#define E 8
#define H 128
#define BM 128   // tokens per expert block (8 waves: 2 row-groups x 4 col-groups)
#define HP 136   // LDS row stride in shorts (272B)
#define RT 8     // tokens per wave in router

typedef __attribute__((ext_vector_type(8))) short short8v;
typedef __attribute__((ext_vector_type(4))) short short4v;
typedef __attribute__((ext_vector_type(4))) float float4v;

__device__ inline short f2bf(float f) {
  union { float f; unsigned u; } v; v.f = f;
  unsigned r = v.u + 0x7fffu + ((v.u >> 16) & 1u);   // RNE
  return (short)(r >> 16);
}
__device__ inline float bf2f(short s) {
  union { unsigned u; float f; } v;
  v.u = ((unsigned)(unsigned short)s) << 16;
  return v.f;
}

// ---------------- K0: swizzle weights into MFMA fragment-contiguous bf16 ----------------
// W1f[e][f=ks*8+t][lane][j]  (ks 0..15, t 0..7)
// W2f[e][f=t*4+ks][lane][j]  (t 0..31,  ks 0..3)   <- t-major
__global__ void k_swizzle(const float* __restrict__ W1, const float* __restrict__ W2,
                          short* __restrict__ W1f, short* __restrict__ W2f) {
  const int e = blockIdx.y;
  const int lane = threadIdx.x & 63;
  const int wv = threadIdx.x >> 6;
  const int r = lane & 15, g = lane >> 4;
  const int which = blockIdx.x >> 4;                 // 0: W1, 1: W2
  const int fbase = ((blockIdx.x & 15) * 4 + wv) * 2;
  if (which == 0) {
#pragma unroll
    for (int f = fbase; f < fbase + 2; ++f) {
      int ks = f >> 3, t = f & 7;
      const float* src = W1 + ((size_t)e * D + ks * 32 + g * 8) * H + t * 16 + r;
      short8v o;
#pragma unroll
      for (int j = 0; j < 8; ++j) o[j] = f2bf(src[(size_t)j * H]);
      *(short8v*)(W1f + (((size_t)e * 128 + f) * 64 + lane) * 8) = o;
    }
  } else {
#pragma unroll
    for (int f = fbase; f < fbase + 2; ++f) {
      int t = f >> 2, ks = f & 3;
      const float* src = W2 + ((size_t)e * H + ks * 32 + g * 8) * D + t * 16 + r;
      short8v o;
#pragma unroll
      for (int j = 0; j < 8; ++j) o[j] = f2bf(src[(size_t)j * D]);
      *(short8v*)(W2f + (((size_t)e * 128 + f) * 64 + lane) * 8) = o;
    }
  }
}

// ---------------- K1: router — one wave per RT tokens, fold-butterfly reduce (fp32 exact) ----------------
__global__ void k_router(const float* __restrict__ x, const float* __restrict__ Wr,
                         const float* __restrict__ br, int* __restrict__ tokE,
                         float* __restrict__ confPart, short* __restrict__ xb) {
  const int lane = threadIdx.x & 63;
  const int wave = threadIdx.x >> 6;
  const int tbase = (blockIdx.x * 4 + wave) * RT;

  float wr[8][8];
  const float4* wrp = reinterpret_cast<const float4*>(Wr) + lane * 16;
#pragma unroll
  for (int j = 0; j < 8; ++j) {
    float4 a = wrp[j * 2 + 0];
    float4 b = wrp[j * 2 + 1];
    wr[j][0] = a.x; wr[j][1] = a.y; wr[j][2] = a.z; wr[j][3] = a.w;
    wr[j][4] = b.x; wr[j][5] = b.y; wr[j][6] = b.z; wr[j][7] = b.w;
  }

  const int myE = ((lane & 1) << 2) | (lane & 2) | ((lane >> 2) & 1);
  const float brv = br[myE];

  float conf = 0.f;

#pragma unroll 2
  for (int tt = 0; tt < RT; ++tt) {
    const int token = tbase + tt;
    const float4* xp = reinterpret_cast<const float4*>(x + (size_t)token * D + lane * 8);
    float4 x0 = xp[0], x1 = xp[1];
    float xv[8] = {x0.x, x0.y, x0.z, x0.w, x1.x, x1.y, x1.z, x1.w};

    if (xb) {
      short8v p;
#pragma unroll
      for (int j = 0; j < 8; ++j) p[j] = f2bf(xv[j]);
      *(short8v*)(xb + (size_t)token * D + lane * 8) = p;
    }

    float v[8] = {0, 0, 0, 0, 0, 0, 0, 0};
#pragma unroll
    for (int j = 0; j < 8; ++j)
#pragma unroll
      for (int e = 0; e < E; ++e)
        v[e] += xv[j] * wr[j][e];

#pragma unroll
    for (int i = 0; i < 4; ++i) {
      float a = v[i] + __shfl_xor(v[i], 1, 64);
      float b = v[i + 4] + __shfl_xor(v[i + 4], 1, 64);
      v[i] = (lane & 1) ? b : a;
    }
#pragma unroll
    for (int i = 0; i < 2; ++i) {
      float a = v[i] + __shfl_xor(v[i], 2, 64);
      float b = v[i + 2] + __shfl_xor(v[i + 2], 2, 64);
      v[i] = (lane & 2) ? b : a;
    }
    {
      float a = v[0] + __shfl_xor(v[0], 4, 64);
      float b = v[1] + __shfl_xor(v[1], 4, 64);
      v[0] = (lane & 4) ? b : a;
    }
    v[0] += __shfl_xor(v[0], 8, 64);
    v[0] += __shfl_xor(v[0], 16, 64);
    v[0] += __shfl_xor(v[0], 32, 64);

    const float logit = v[0] + brv;

    float m1 = logit; int i1 = myE;
#pragma unroll
    for (int m = 1; m <= 4; m <<= 1) {
      float om = __shfl_xor(m1, m, 64);
      int oi = __shfl_xor(i1, m, 64);
      bool take = (om > m1) || (om == m1 && oi < i1);
      m1 = take ? om : m1;
      i1 = take ? oi : i1;
    }
    float s1 = (myE == i1) ? -1e30f : logit; int j1 = myE;
#pragma unroll
    for (int m = 1; m <= 4; m <<= 1) {
      float om = __shfl_xor(s1, m, 64);
      int oi = __shfl_xor(j1, m, 64);
      bool take = (om > s1) || (om == s1 && oi < j1);
      s1 = take ? om : s1;
      j1 = take ? oi : j1;
    }

    if (lane == 0) {
      tokE[token * 2 + 0] = i1;
      tokE[token * 2 + 1] = j1;
    }
    conf += m1;
  }

  __shared__ float cf[4];
  if (lane == 0) cf[wave] = conf;
  __syncthreads();
  if (threadIdx.x == 0) confPart[blockIdx.x] = cf[0] + cf[1] + cf[2] + cf[3];
}

// ---------------- K2: per-chunk (256 tokens) expert counts ----------------
__global__ void k_count(const int* __restrict__ tokE, int* __restrict__ chunkCnt) {
  __shared__ int c[E];
  if (threadIdx.x < E) c[threadIdx.x] = 0;
  __syncthreads();
  int token = blockIdx.x * 256 + threadIdx.x;
  atomicAdd(&c[tokE[token * 2 + 0]], 1);
  atomicAdd(&c[tokE[token * 2 + 1]], 1);
  __syncthreads();
  if (threadIdx.x < E) chunkCnt[blockIdx.x * E + threadIdx.x] = c[threadIdx.x];
}

// ---------------- K3: wave-parallel scan + stats ----------------
__global__ void k_scan(const int* __restrict__ chunkCnt, const float* __restrict__ confPart,
                       int* __restrict__ chunkOff, int* __restrict__ kept,
                       float* __restrict__ outTail, int nConf, int cap, int nTok) {
  const int lane = threadIdx.x & 63;
  const int e = threadIdx.x >> 6;
  __shared__ int keptS[E];

  int v0 = chunkCnt[lane * E + e];
  int v1 = chunkCnt[(64 + lane) * E + e];
  int s0 = v0, s1 = v1;
#pragma unroll
  for (int off = 1; off < 64; off <<= 1) {
    int t0 = __shfl_up(s0, off, 64);
    int t1 = __shfl_up(s1, off, 64);
    if (lane >= off) { s0 += t0; s1 += t1; }
  }
  int tot0 = __shfl(s0, 63, 64);
  int total = tot0 + __shfl(s1, 63, 64);
  chunkOff[lane * E + e] = s0 - v0;
  chunkOff[(64 + lane) * E + e] = tot0 + s1 - v1;
  if (lane == 0) {
    int k = min(total, cap);
    kept[e] = k;
    keptS[e] = k;
  }

  __shared__ float s[512];
  float a = 0.f;
  for (int i = threadIdx.x; i < nConf; i += 512) a += confPart[i];
  s[threadIdx.x] = a;
  __syncthreads();
  for (int st = 256; st > 0; st >>= 1) {
    if (threadIdx.x < st) s[threadIdx.x] += s[threadIdx.x + st];
    __syncthreads();
  }
  if (threadIdx.x == 0) {
    float tot = 0.f, ld[E];
    for (int i = 0; i < E; ++i) { ld[i] = (float)keptS[i]; tot += ld[i]; }
    float denom = tot + 1e-8f;
    float loss = 0.f;
    for (int i = 0; i < E; ++i) {
      float dist = ld[i] / denom;
      loss += dist * logf(dist + 1e-8f);
      outTail[1 + i] = dist;
    }
    outTail[0] = loss;
    outTail[1 + E] = s[0] / (float)nTok;
  }
}

// ---------------- K4: rank assignment + dispatch lists + token->slot map ----------------
__global__ void k_dispatch(const int* __restrict__ tokE, const int* __restrict__ chunkOff,
                           int* __restrict__ expList, int2* __restrict__ tokSlot, int cap) {
  const int lane = threadIdx.x & 63;
  const int wave = threadIdx.x >> 6;
  const int token = blockIdx.x * 256 + threadIdx.x;
  const int e0 = tokE[token * 2 + 0];
  const int e1 = tokE[token * 2 + 1];
  __shared__ int wcnt[4][E];
  unsigned long long lt = (lane == 63) ? 0x7fffffffffffffffull : ((1ull << lane) - 1ull);
  int r0 = 0, r1 = 0;
#pragma unroll
  for (int e = 0; e < E; ++e) {
    unsigned long long b0 = __ballot(e0 == e);
    unsigned long long b1 = __ballot(e1 == e);
    unsigned long long m = b0 | b1;
    if (e0 == e) r0 = __popcll(m & lt);
    if (e1 == e) r1 = __popcll(m & lt);
    if (lane == 0) wcnt[wave][e] = __popcll(m);
  }
  __syncthreads();
  int base0 = chunkOff[blockIdx.x * E + e0];
  int base1 = chunkOff[blockIdx.x * E + e1];
  for (int w = 0; w < wave; ++w) {
    base0 += wcnt[w][e0];
    base1 += wcnt[w][e1];
  }
  int g0 = base0 + r0;
  int g1 = base1 + r1;
  if (g0 < cap) expList[e0 * cap + g0] = token;
  if (g1 < cap) expList[e1 * cap + g1] = token;
  tokSlot[token] = make_int2(g0 < cap ? e0 * cap + g0 : -1,
                             g1 < cap ? e1 * cap + g1 : -1);
}

// ---------------- K5: per-expert FFN via MFMA, barrier-minimal ----------------
// 8 waves = (rowg 0..1) x (ng 0..3). x gathered to registers (no x-LDS, no
// per-phase barriers). Only 2 block barriers: toks, h handoff. LDS ~35KB.
template <bool USE_XB>
__global__ __launch_bounds__(512) void k_expert_mfma(
    const short* __restrict__ xb, const float* __restrict__ x,
    const short* __restrict__ W1f, const float* __restrict__ b1,
    const short* __restrict__ W2f, const float* __restrict__ b2,
    const int* __restrict__ expList, const int* __restrict__ kept,
    short* __restrict__ yscr, int cap) {
  const int e = blockIdx.y;
  const int cnt = kept[e];
  const int t0 = blockIdx.x * BM;
  if (t0 >= cnt) return;
  const int lane = threadIdx.x & 63;
  const int wave = threadIdx.x >> 6;   // 0..7
  const int rowg = wave >> 2;          // 0..1 -> rows [rowg*64, rowg*64+64)
  const int ng = wave & 3;             // 0..3 -> output-column quarter
  const int n15 = lane & 15;
  const int grp = lane >> 4;
  const int kg = grp * 8;

  __shared__ int toks[BM];
  __shared__ short hs[BM][HP];

  if (threadIdx.x < BM) {
    int idx = min(t0 + (int)threadIdx.x, cnt - 1);
    toks[threadIdx.x] = expList[e * cap + idx];
  }
  __syncthreads();

  const short* w1 = W1f + (size_t)e * (128 * 512);
  const short* w2 = W2f + (size_t)e * (128 * 512);

  // per-lane x row bases for this wave's 4 row-tiles
  const short* xrB[4];
  const float* xrF[4];
#pragma unroll
  for (int r = 0; r < 4; ++r) {
    int row = toks[rowg * 64 + r * 16 + n15];
    if (USE_XB) xrB[r] = xb + (size_t)row * D + kg;
    else        xrF[r] = x + (size_t)row * D + kg;
  }

  float4v acc[4][2];
#pragma unroll
  for (int r = 0; r < 4; ++r)
#pragma unroll
    for (int t = 0; t < 2; ++t)
      acc[r][t] = (float4v){0.f, 0.f, 0.f, 0.f};

  // ---- layer 1: 16 k-steps, no barriers; loads pipeline freely ----
#pragma unroll
  for (int ks = 0; ks < 16; ++ks) {
    short8v xf[4];
    if (USE_XB) {
#pragma unroll
      for (int r = 0; r < 4; ++r)
        xf[r] = *(const short8v*)(xrB[r] + ks * 32);
    } else {
#pragma unroll
      for (int r = 0; r < 4; ++r) {
        float4 a0 = *(const float4*)(xrF[r] + ks * 32);
        float4 a1 = *(const float4*)(xrF[r] + ks * 32 + 4);
        short8v f;
        f[0] = f2bf(a0.x); f[1] = f2bf(a0.y); f[2] = f2bf(a0.z); f[3] = f2bf(a0.w);
        f[4] = f2bf(a1.x); f[5] = f2bf(a1.y); f[6] = f2bf(a1.z); f[7] = f2bf(a1.w);
        xf[r] = f;
      }
    }
    short8v wf[2];
#pragma unroll
    for (int t = 0; t < 2; ++t)
      wf[t] = *(const short8v*)(w1 + (size_t)(ks * 8 + ng * 2 + t) * 512 + lane * 8);
#pragma unroll
    for (int t = 0; t < 2; ++t)
#pragma unroll
      for (int r = 0; r < 4; ++r)
        acc[r][t] = __builtin_amdgcn_mfma_f32_16x16x32_bf16(wf[t], xf[r], acc[r][t], 0, 0, 0);
  }

  // ---- h = relu(acc + b1) -> hs; wave writes 4 row-tiles x 2 col-tiles ----
#pragma unroll
  for (int t = 0; t < 2; ++t) {
    int tg = ng * 2 + t;
    float4 bb = *(const float4*)(b1 + e * H + tg * 16 + grp * 4);
#pragma unroll
    for (int r = 0; r < 4; ++r) {
      short4v p;
      p[0] = f2bf(fmaxf(acc[r][t][0] + bb.x, 0.f));
      p[1] = f2bf(fmaxf(acc[r][t][1] + bb.y, 0.f));
      p[2] = f2bf(fmaxf(acc[r][t][2] + bb.z, 0.f));
      p[3] = f2bf(fmaxf(acc[r][t][3] + bb.w, 0.f));
      *(short4v*)(&hs[rowg * 64 + r * 16 + n15][tg * 16 + grp * 4]) = p;
    }
  }
  __syncthreads();

  // ---- layer 2: 2 passes, each = 2 row-tiles x 8 d-tiles (ng split of 32) ----
#pragma unroll
  for (int rp = 0; rp < 2; ++rp) {
    const int rbase = rowg * 64 + rp * 32;
    short8v a4[2][4];
#pragma unroll
    for (int ri = 0; ri < 2; ++ri)
#pragma unroll
      for (int ks = 0; ks < 4; ++ks)
        a4[ri][ks] = *(const short8v*)(&hs[rbase + ri * 16 + n15][ks * 32 + kg]);

    short* yrow0 = yscr + ((size_t)(e * cap + t0 + rbase + n15)) * D;
    short* yrow1 = yrow0 + (size_t)16 * D;
#pragma unroll 4
    for (int tt = 0; tt < 8; ++tt) {
      const int t = ng * 8 + tt;
      short8v wf[4];
#pragma unroll
      for (int ks = 0; ks < 4; ++ks)
        wf[ks] = *(const short8v*)(w2 + (size_t)(t * 4 + ks) * 512 + lane * 8);
      float4v y0 = (float4v){0.f, 0.f, 0.f, 0.f};
      float4v y1 = (float4v){0.f, 0.f, 0.f, 0.f};
#pragma unroll
      for (int ks = 0; ks < 4; ++ks) {
        y0 = __builtin_amdgcn_mfma_f32_16x16x32_bf16(wf[ks], a4[0][ks], y0, 0, 0, 0);
        y1 = __builtin_amdgcn_mfma_f32_16x16x32_bf16(wf[ks], a4[1][ks], y1, 0, 0, 0);
      }
      float4 bb = *(const float4*)(b2 + e * D + t * 16 + grp * 4);
      short4v p0, p1;
      p0[0] = f2bf(y0[0] + bb.x);
      p0[1] = f2bf(y0[1] + bb.y);
      p0[2] = f2bf(y0[2] + bb.z);
      p0[3] = f2bf(y0[3] + bb.w);
      p1[0] = f2bf(y1[0] + bb.x);
      p1[1] = f2bf(y1[1] + bb.y);
      p1[2] = f2bf(y1[2] + bb.z);
      p1[3] = f2bf(y1[3] + bb.w);
      *(short4v*)(yrow0 + t * 16 + grp * 4) = p0;
      *(short4v*)(yrow1 + t * 16 + grp * 4) = p1;
    }
  }
}

// ---------------- K6: combine — out[token] = sum of kept slots (or 0) ----------------
__global__ void k_combine(const short* __restrict__ yscr, const int2* __restrict__ tokSlot,
                          float* __restrict__ out) {
  const int idx = blockIdx.x * 256 + threadIdx.x;
  const int token = idx >> 7;
  const int c4 = idx & 127;
  int2 sl = tokSlot[token];
  float4 r = make_float4(0.f, 0.f, 0.f, 0.f);
  if (sl.x >= 0) {
    short4v y = *(const short4v*)(yscr + (size_t)sl.x * D + c4 * 4);
    r.x += bf2f(y[0]); r.y += bf2f(y[1]); r.z += bf2f(y[2]); r.w += bf2f(y[3]);
  }
  if (sl.y >= 0) {
    short4v y = *(const short4v*)(yscr + (size_t)sl.y * D + c4 * 4);
    r.x += bf2f(y[0]); r.y += bf2f(y[1]); r.z += bf2f(y[2]); r.w += bf2f(y[3]);
  }
  reinterpret_cast<float4*>(out)[idx] = r;
}

extern "C" void kernel_launch(void* const* d_in, const int* in_sizes, int n_in,
                              void* d_out, int out_size, void* d_ws, size_t ws_size,
                              hipStream_t stream) {
  const float* x  = (const float*)d_in[0];
  const float* Wr = (const float*)d_in[1];
  const float* br = (const float*)d_in[2];
  const float* W1 = (const float*)d_in[3];
  const float* b1 = (const float*)d_in[4];
  const float* W2 = (const float*)d_in[5];
  const float* b2 = (const float*)d_in[6];
  float* out = (float*)d_out;

  const int N = in_sizes[0] / D;                 // 32768
  const int cap = (int)(1.25f * (float)(N / E)); // 5120
  const int chunks = N / 256;                    // 128
  const int rblocks = N / (4 * RT);              // 1024 router blocks

  int* tokE = (int*)d_ws;                                    // N*2
  float* confPart = (float*)(tokE + (size_t)N * 2);          // rblocks
  int* chunkCnt = (int*)(confPart + rblocks);                // chunks*E
  int* chunkOff = chunkCnt + chunks * E;                     // chunks*E
  int* kept = chunkOff + chunks * E;                         // E
  int2* tokSlot = (int2*)(kept + E);                         // N int2
  int* expList = (int*)(tokSlot + N);                        // E*cap
  short* W1f = (short*)(expList + (size_t)E * cap);          // [E][128][64][8]
  short* W2f = W1f + (size_t)E * H * D;                      // [E][128][64][8]
  short* yscr = W2f + (size_t)E * H * D;                     // [E*cap][D] bf16
  short* xb = yscr + (size_t)E * cap * D;                    // [N][D] bf16 (optional)

  const size_t needed = (size_t)((char*)(xb + (size_t)N * D) - (char*)d_ws);
  const bool useXB = ws_size >= needed;

  k_swizzle<<<dim3(32, E), 256, 0, stream>>>(W1, W2, W1f, W2f);

  k_router<<<rblocks, 256, 0, stream>>>(x, Wr, br, tokE, confPart,
                                        useXB ? xb : nullptr);
  k_count<<<chunks, 256, 0, stream>>>(tokE, chunkCnt);
  k_scan<<<1, 512, 0, stream>>>(chunkCnt, confPart, chunkOff, kept,
                                out + (size_t)N * D, rblocks, cap, N);
  k_dispatch<<<chunks, 256, 0, stream>>>(tokE, chunkOff, expList, tokSlot, cap);

  const int tiles = (cap + BM - 1) / BM;        // 40
  dim3 g5(tiles, E);                            // 320 blocks x 8 waves
  if (useXB)
    k_expert_mfma<true><<<g5, 512, 0, stream>>>(xb, x, W1f, b1, W2f, b2,
                                                expList, kept, yscr, cap);
  else
    k_expert_mfma<false><<<g5, 512, 0, stream>>>(nullptr, x, W1f, b1, W2f, b2,
                                                 expList, kept, yscr, cap);

  k_combine<<<(N * D / 4) / 256, 256, 0, stream>>>(yscr, tokSlot, out);
}

// Round 17
// 107.549 us; speedup vs baseline: 1.1727x; 1.1727x over previous
//
#include <hip/hip_runtime.h>

#define D 512
#define E 8
#define H 128
#define BM 128   // tokens per expert block (8 waves: 2 row-groups x 4 col-groups)
#define HP 136   // LDS row stride in shorts (272B)
#define RT 8     // tokens per wave in router

typedef __attribute__((ext_vector_type(8))) short short8v;
typedef __attribute__((ext_vector_type(4))) short short4v;
typedef __attribute__((ext_vector_type(4))) float float4v;

__device__ inline short f2bf(float f) {
  union { float f; unsigned u; } v; v.f = f;
  unsigned r = v.u + 0x7fffu + ((v.u >> 16) & 1u);   // RNE
  return (short)(r >> 16);
}
__device__ inline float bf2f(short s) {
  union { unsigned u; float f; } v;
  v.u = ((unsigned)(unsigned short)s) << 16;
  return v.f;
}
__device__ inline void gload_lds4(const void* g, void* l) {
  __builtin_amdgcn_global_load_lds(
      (const __attribute__((address_space(1))) unsigned int*)g,
      (__attribute__((address_space(3))) unsigned int*)l, 4, 0, 0);
}

// ---------------- K0: swizzle weights into MFMA fragment-contiguous bf16 ----------------
// W1f[e][f=ks*8+t][lane][j]  (ks 0..15, t 0..7)
// W2f[e][f=t*4+ks][lane][j]  (t 0..31,  ks 0..3)   <- t-major
__global__ void k_swizzle(const float* __restrict__ W1, const float* __restrict__ W2,
                          short* __restrict__ W1f, short* __restrict__ W2f) {
  const int e = blockIdx.y;
  const int lane = threadIdx.x & 63;
  const int wv = threadIdx.x >> 6;
  const int r = lane & 15, g = lane >> 4;
  const int which = blockIdx.x >> 4;                 // 0: W1, 1: W2
  const int fbase = ((blockIdx.x & 15) * 4 + wv) * 2;
  if (which == 0) {
#pragma unroll
    for (int f = fbase; f < fbase + 2; ++f) {
      int ks = f >> 3, t = f & 7;
      const float* src = W1 + ((size_t)e * D + ks * 32 + g * 8) * H + t * 16 + r;
      short8v o;
#pragma unroll
      for (int j = 0; j < 8; ++j) o[j] = f2bf(src[(size_t)j * H]);
      *(short8v*)(W1f + (((size_t)e * 128 + f) * 64 + lane) * 8) = o;
    }
  } else {
#pragma unroll
    for (int f = fbase; f < fbase + 2; ++f) {
      int t = f >> 2, ks = f & 3;
      const float* src = W2 + ((size_t)e * H + ks * 32 + g * 8) * D + t * 16 + r;
      short8v o;
#pragma unroll
      for (int j = 0; j < 8; ++j) o[j] = f2bf(src[(size_t)j * D]);
      *(short8v*)(W2f + (((size_t)e * 128 + f) * 64 + lane) * 8) = o;
    }
  }
}

// ---------------- K1: router — one wave per RT tokens, fold-butterfly reduce (fp32 exact) ----------------
__global__ void k_router(const float* __restrict__ x, const float* __restrict__ Wr,
                         const float* __restrict__ br, int* __restrict__ tokE,
                         float* __restrict__ confPart, short* __restrict__ xb) {
  const int lane = threadIdx.x & 63;
  const int wave = threadIdx.x >> 6;
  const int tbase = (blockIdx.x * 4 + wave) * RT;

  float wr[8][8];
  const float4* wrp = reinterpret_cast<const float4*>(Wr) + lane * 16;
#pragma unroll
  for (int j = 0; j < 8; ++j) {
    float4 a = wrp[j * 2 + 0];
    float4 b = wrp[j * 2 + 1];
    wr[j][0] = a.x; wr[j][1] = a.y; wr[j][2] = a.z; wr[j][3] = a.w;
    wr[j][4] = b.x; wr[j][5] = b.y; wr[j][6] = b.z; wr[j][7] = b.w;
  }

  const int myE = ((lane & 1) << 2) | (lane & 2) | ((lane >> 2) & 1);
  const float brv = br[myE];

  float conf = 0.f;

#pragma unroll 2
  for (int tt = 0; tt < RT; ++tt) {
    const int token = tbase + tt;
    const float4* xp = reinterpret_cast<const float4*>(x + (size_t)token * D + lane * 8);
    float4 x0 = xp[0], x1 = xp[1];
    float xv[8] = {x0.x, x0.y, x0.z, x0.w, x1.x, x1.y, x1.z, x1.w};

    if (xb) {
      short8v p;
#pragma unroll
      for (int j = 0; j < 8; ++j) p[j] = f2bf(xv[j]);
      *(short8v*)(xb + (size_t)token * D + lane * 8) = p;
    }

    float v[8] = {0, 0, 0, 0, 0, 0, 0, 0};
#pragma unroll
    for (int j = 0; j < 8; ++j)
#pragma unroll
      for (int e = 0; e < E; ++e)
        v[e] += xv[j] * wr[j][e];

#pragma unroll
    for (int i = 0; i < 4; ++i) {
      float a = v[i] + __shfl_xor(v[i], 1, 64);
      float b = v[i + 4] + __shfl_xor(v[i + 4], 1, 64);
      v[i] = (lane & 1) ? b : a;
    }
#pragma unroll
    for (int i = 0; i < 2; ++i) {
      float a = v[i] + __shfl_xor(v[i], 2, 64);
      float b = v[i + 2] + __shfl_xor(v[i + 2], 2, 64);
      v[i] = (lane & 2) ? b : a;
    }
    {
      float a = v[0] + __shfl_xor(v[0], 4, 64);
      float b = v[1] + __shfl_xor(v[1], 4, 64);
      v[0] = (lane & 4) ? b : a;
    }
    v[0] += __shfl_xor(v[0], 8, 64);
    v[0] += __shfl_xor(v[0], 16, 64);
    v[0] += __shfl_xor(v[0], 32, 64);

    const float logit = v[0] + brv;

    float m1 = logit; int i1 = myE;
#pragma unroll
    for (int m = 1; m <= 4; m <<= 1) {
      float om = __shfl_xor(m1, m, 64);
      int oi = __shfl_xor(i1, m, 64);
      bool take = (om > m1) || (om == m1 && oi < i1);
      m1 = take ? om : m1;
      i1 = take ? oi : i1;
    }
    float s1 = (myE == i1) ? -1e30f : logit; int j1 = myE;
#pragma unroll
    for (int m = 1; m <= 4; m <<= 1) {
      float om = __shfl_xor(s1, m, 64);
      int oi = __shfl_xor(j1, m, 64);
      bool take = (om > s1) || (om == s1 && oi < j1);
      s1 = take ? om : s1;
      j1 = take ? oi : j1;
    }

    if (lane == 0) {
      tokE[token * 2 + 0] = i1;
      tokE[token * 2 + 1] = j1;
    }
    conf += m1;
  }

  __shared__ float cf[4];
  if (lane == 0) cf[wave] = conf;
  __syncthreads();
  if (threadIdx.x == 0) confPart[blockIdx.x] = cf[0] + cf[1] + cf[2] + cf[3];
}

// ---------------- K2: per-chunk (256 tokens) expert counts ----------------
__global__ void k_count(const int* __restrict__ tokE, int* __restrict__ chunkCnt) {
  __shared__ int c[E];
  if (threadIdx.x < E) c[threadIdx.x] = 0;
  __syncthreads();
  int token = blockIdx.x * 256 + threadIdx.x;
  atomicAdd(&c[tokE[token * 2 + 0]], 1);
  atomicAdd(&c[tokE[token * 2 + 1]], 1);
  __syncthreads();
  if (threadIdx.x < E) chunkCnt[blockIdx.x * E + threadIdx.x] = c[threadIdx.x];
}

// ---------------- K3: wave-parallel scan + stats ----------------
__global__ void k_scan(const int* __restrict__ chunkCnt, const float* __restrict__ confPart,
                       int* __restrict__ chunkOff, int* __restrict__ kept,
                       float* __restrict__ outTail, int nConf, int cap, int nTok) {
  const int lane = threadIdx.x & 63;
  const int e = threadIdx.x >> 6;
  __shared__ int keptS[E];

  int v0 = chunkCnt[lane * E + e];
  int v1 = chunkCnt[(64 + lane) * E + e];
  int s0 = v0, s1 = v1;
#pragma unroll
  for (int off = 1; off < 64; off <<= 1) {
    int t0 = __shfl_up(s0, off, 64);
    int t1 = __shfl_up(s1, off, 64);
    if (lane >= off) { s0 += t0; s1 += t1; }
  }
  int tot0 = __shfl(s0, 63, 64);
  int total = tot0 + __shfl(s1, 63, 64);
  chunkOff[lane * E + e] = s0 - v0;
  chunkOff[(64 + lane) * E + e] = tot0 + s1 - v1;
  if (lane == 0) {
    int k = min(total, cap);
    kept[e] = k;
    keptS[e] = k;
  }

  __shared__ float s[512];
  float a = 0.f;
  for (int i = threadIdx.x; i < nConf; i += 512) a += confPart[i];
  s[threadIdx.x] = a;
  __syncthreads();
  for (int st = 256; st > 0; st >>= 1) {
    if (threadIdx.x < st) s[threadIdx.x] += s[threadIdx.x + st];
    __syncthreads();
  }
  if (threadIdx.x == 0) {
    float tot = 0.f, ld[E];
    for (int i = 0; i < E; ++i) { ld[i] = (float)keptS[i]; tot += ld[i]; }
    float denom = tot + 1e-8f;
    float loss = 0.f;
    for (int i = 0; i < E; ++i) {
      float dist = ld[i] / denom;
      loss += dist * logf(dist + 1e-8f);
      outTail[1 + i] = dist;
    }
    outTail[0] = loss;
    outTail[1 + E] = s[0] / (float)nTok;
  }
}

// ---------------- K4: rank assignment + dispatch lists + token->slot map ----------------
__global__ void k_dispatch(const int* __restrict__ tokE, const int* __restrict__ chunkOff,
                           int* __restrict__ expList, int2* __restrict__ tokSlot, int cap) {
  const int lane = threadIdx.x & 63;
  const int wave = threadIdx.x >> 6;
  const int token = blockIdx.x * 256 + threadIdx.x;
  const int e0 = tokE[token * 2 + 0];
  const int e1 = tokE[token * 2 + 1];
  __shared__ int wcnt[4][E];
  unsigned long long lt = (lane == 63) ? 0x7fffffffffffffffull : ((1ull << lane) - 1ull);
  int r0 = 0, r1 = 0;
#pragma unroll
  for (int e = 0; e < E; ++e) {
    unsigned long long b0 = __ballot(e0 == e);
    unsigned long long b1 = __ballot(e1 == e);
    unsigned long long m = b0 | b1;
    if (e0 == e) r0 = __popcll(m & lt);
    if (e1 == e) r1 = __popcll(m & lt);
    if (lane == 0) wcnt[wave][e] = __popcll(m);
  }
  __syncthreads();
  int base0 = chunkOff[blockIdx.x * E + e0];
  int base1 = chunkOff[blockIdx.x * E + e1];
  for (int w = 0; w < wave; ++w) {
    base0 += wcnt[w][e0];
    base1 += wcnt[w][e1];
  }
  int g0 = base0 + r0;
  int g1 = base1 + r1;
  if (g0 < cap) expList[e0 * cap + g0] = token;
  if (g1 < cap) expList[e1 * cap + g1] = token;
  tokSlot[token] = make_int2(g0 < cap ? e0 * cap + g0 : -1,
                             g1 < cap ? e1 * cap + g1 : -1);
}

// ---------------- K5: per-expert FFN via MFMA ----------------
// 8 waves = (rowg 0..1) x (ng 0..3). x LDS-staged (4-phase dbuf).
// L1: xf[4][4] hoisted per phase + 1-ahead W1 prefetch (named regs).
// L2: fused single pass over 4 row-tiles (each W2 frag -> 4 MFMAs) + 1-ahead prefetch.
template <bool USE_XB>
__global__ __launch_bounds__(512, 1) void k_expert_mfma(
    const short* __restrict__ xb, const float* __restrict__ x,
    const short* __restrict__ W1f, const float* __restrict__ b1,
    const short* __restrict__ W2f, const float* __restrict__ b2,
    const int* __restrict__ expList, const int* __restrict__ kept,
    short* __restrict__ yscr, int cap) {
  const int e = blockIdx.y;
  const int cnt = kept[e];
  const int t0 = blockIdx.x * BM;
  if (t0 >= cnt) return;
  const int lane = threadIdx.x & 63;
  const int wave = threadIdx.x >> 6;   // 0..7
  const int rowg = wave >> 2;          // 0..1 -> rows [rowg*64, rowg*64+64)
  const int ng = wave & 3;             // 0..3 -> output-column quarter
  const int n15 = lane & 15;
  const int grp = lane >> 4;
  const int kg = grp * 8;

  __shared__ int toks[BM];
  __shared__ short sbuf[2 * BM * HP];   // x phase double-buffer; buf0 reused as hs

  if (threadIdx.x < BM) {
    int idx = min(t0 + (int)threadIdx.x, cnt - 1);
    toks[threadIdx.x] = expList[e * cap + idx];
  }
  __syncthreads();

  const short* w1 = W1f + (size_t)e * (128 * 512);
  const short* w2 = W2f + (size_t)e * (128 * 512);
  const short* w1p = w1 + (size_t)(ng * 2) * 512 + lane * 8;   // + ks*8*512 per k-step

  float4v acc[4][2];
#pragma unroll
  for (int r = 0; r < 4; ++r)
#pragma unroll
    for (int t = 0; t < 2; ++t)
      acc[r][t] = (float4v){0.f, 0.f, 0.f, 0.f};

  if (USE_XB) {
    // stage phase p: token row bytes [p*256, +256) -> sbuf[p&1][ti][..]; 16 rows/wave
    auto stageX = [&](int p) {
#pragma unroll
      for (int j = 0; j < 16; ++j) {
        int ti = wave * 16 + j;
        const short* src = xb + (size_t)toks[ti] * D + p * 128 + lane * 2;
        short* dst = &sbuf[(p & 1) * (BM * HP) + ti * HP];
        gload_lds4(src, dst);
      }
    };
    stageX(0);
    __syncthreads();
#pragma unroll
    for (int p = 0; p < 4; ++p) {
      if (p < 3) stageX(p + 1);
      const short* sb = &sbuf[(p & 1) * (BM * HP)];
      // hoist ALL x fragments of this phase (static indices, fully unrolled)
      short8v xf[4][4];
#pragma unroll
      for (int ksl = 0; ksl < 4; ++ksl)
#pragma unroll
        for (int r = 0; r < 4; ++r)
          xf[ksl][r] = *(const short8v*)&sb[(rowg * 64 + r * 16 + n15) * HP + ksl * 32 + kg];
      const short* wp = w1p + (size_t)(p * 4) * 8 * 512;
      short8v wc0 = *(const short8v*)(wp);
      short8v wc1 = *(const short8v*)(wp + 512);
#pragma unroll
      for (int ksl = 0; ksl < 4; ++ksl) {
        short8v wn0 = wc0, wn1 = wc1;
        if (ksl < 3) {
          wn0 = *(const short8v*)(wp + (size_t)(ksl + 1) * 8 * 512);
          wn1 = *(const short8v*)(wp + (size_t)(ksl + 1) * 8 * 512 + 512);
        }
#pragma unroll
        for (int r = 0; r < 4; ++r)
          acc[r][0] = __builtin_amdgcn_mfma_f32_16x16x32_bf16(wc0, xf[ksl][r], acc[r][0], 0, 0, 0);
#pragma unroll
        for (int r = 0; r < 4; ++r)
          acc[r][1] = __builtin_amdgcn_mfma_f32_16x16x32_bf16(wc1, xf[ksl][r], acc[r][1], 0, 0, 0);
        wc0 = wn0; wc1 = wn1;
      }
      __syncthreads();
    }
  } else {
    // fallback: per-lane gather from fp32 x (correctness path)
#pragma unroll 1
    for (int ks = 0; ks < 16; ++ks) {
      short8v xf[4];
#pragma unroll
      for (int r = 0; r < 4; ++r) {
        const float* xr = x + (size_t)toks[rowg * 64 + r * 16 + n15] * D + kg + ks * 32;
        float4 a0 = *(const float4*)(xr);
        float4 a1 = *(const float4*)(xr + 4);
        short8v f;
        f[0] = f2bf(a0.x); f[1] = f2bf(a0.y); f[2] = f2bf(a0.z); f[3] = f2bf(a0.w);
        f[4] = f2bf(a1.x); f[5] = f2bf(a1.y); f[6] = f2bf(a1.z); f[7] = f2bf(a1.w);
        xf[r] = f;
      }
      short8v wf0 = *(const short8v*)(w1p + (size_t)ks * 8 * 512);
      short8v wf1 = *(const short8v*)(w1p + (size_t)ks * 8 * 512 + 512);
#pragma unroll
      for (int r = 0; r < 4; ++r) {
        acc[r][0] = __builtin_amdgcn_mfma_f32_16x16x32_bf16(wf0, xf[r], acc[r][0], 0, 0, 0);
        acc[r][1] = __builtin_amdgcn_mfma_f32_16x16x32_bf16(wf1, xf[r], acc[r][1], 0, 0, 0);
      }
    }
    __syncthreads();
  }

  // ---- h = relu(acc + b1) -> sbuf buffer0; wave writes 4 row-tiles x 2 col-tiles ----
#pragma unroll
  for (int t = 0; t < 2; ++t) {
    int tg = ng * 2 + t;
    float4 bb = *(const float4*)(b1 + e * H + tg * 16 + grp * 4);
#pragma unroll
    for (int r = 0; r < 4; ++r) {
      short4v p;
      p[0] = f2bf(fmaxf(acc[r][t][0] + bb.x, 0.f));
      p[1] = f2bf(fmaxf(acc[r][t][1] + bb.y, 0.f));
      p[2] = f2bf(fmaxf(acc[r][t][2] + bb.z, 0.f));
      p[3] = f2bf(fmaxf(acc[r][t][3] + bb.w, 0.f));
      *(short4v*)(&sbuf[(rowg * 64 + r * 16 + n15) * HP + tg * 16 + grp * 4]) = p;
    }
  }
  __syncthreads();

  // ---- layer 2: fused single pass — 4 row-tiles x 8 d-tiles (1 load : 4 MFMA) ----
  short8v a4[4][4];   // [ri][ks]
#pragma unroll
  for (int ri = 0; ri < 4; ++ri)
#pragma unroll
    for (int ks = 0; ks < 4; ++ks)
      a4[ri][ks] = *(const short8v*)(&sbuf[(rowg * 64 + ri * 16 + n15) * HP + ks * 32 + kg]);

  const short* w2p = w2 + (size_t)(ng * 8 * 4) * 512 + lane * 8;   // + tt*4*512, + ks*512
  short* yr0 = yscr + ((size_t)(e * cap + t0 + rowg * 64 + n15)) * D;

  short8v wc0 = *(const short8v*)(w2p + 0 * 512);
  short8v wc1 = *(const short8v*)(w2p + 1 * 512);
  short8v wc2 = *(const short8v*)(w2p + 2 * 512);
  short8v wc3 = *(const short8v*)(w2p + 3 * 512);
#pragma unroll
  for (int tt = 0; tt < 8; ++tt) {
    short8v wn0 = wc0, wn1 = wc1, wn2 = wc2, wn3 = wc3;
    if (tt < 7) {
      const short* np = w2p + (size_t)(tt + 1) * 4 * 512;
      wn0 = *(const short8v*)(np + 0 * 512);
      wn1 = *(const short8v*)(np + 1 * 512);
      wn2 = *(const short8v*)(np + 2 * 512);
      wn3 = *(const short8v*)(np + 3 * 512);
    }
    const int t = ng * 8 + tt;
    float4 bb = *(const float4*)(b2 + e * D + t * 16 + grp * 4);
#pragma unroll
    for (int ri = 0; ri < 4; ++ri) {
      float4v y = (float4v){0.f, 0.f, 0.f, 0.f};
      y = __builtin_amdgcn_mfma_f32_16x16x32_bf16(wc0, a4[ri][0], y, 0, 0, 0);
      y = __builtin_amdgcn_mfma_f32_16x16x32_bf16(wc1, a4[ri][1], y, 0, 0, 0);
      y = __builtin_amdgcn_mfma_f32_16x16x32_bf16(wc2, a4[ri][2], y, 0, 0, 0);
      y = __builtin_amdgcn_mfma_f32_16x16x32_bf16(wc3, a4[ri][3], y, 0, 0, 0);
      short4v pv;
      pv[0] = f2bf(y[0] + bb.x);
      pv[1] = f2bf(y[1] + bb.y);
      pv[2] = f2bf(y[2] + bb.z);
      pv[3] = f2bf(y[3] + bb.w);
      *(short4v*)(yr0 + (size_t)ri * 16 * D + t * 16 + grp * 4) = pv;
    }
    wc0 = wn0; wc1 = wn1; wc2 = wn2; wc3 = wn3;
  }
}

// ---------------- K6: combine — out[token] = sum of kept slots (or 0) ----------------
__global__ void k_combine(const short* __restrict__ yscr, const int2* __restrict__ tokSlot,
                          float* __restrict__ out) {
  const int idx = blockIdx.x * 256 + threadIdx.x;
  const int token = idx >> 7;
  const int c4 = idx & 127;
  int2 sl = tokSlot[token];
  float4 r = make_float4(0.f, 0.f, 0.f, 0.f);
  if (sl.x >= 0) {
    short4v y = *(const short4v*)(yscr + (size_t)sl.x * D + c4 * 4);
    r.x += bf2f(y[0]); r.y += bf2f(y[1]); r.z += bf2f(y[2]); r.w += bf2f(y[3]);
  }
  if (sl.y >= 0) {
    short4v y = *(const short4v*)(yscr + (size_t)sl.y * D + c4 * 4);
    r.x += bf2f(y[0]); r.y += bf2f(y[1]); r.z += bf2f(y[2]); r.w += bf2f(y[3]);
  }
  reinterpret_cast<float4*>(out)[idx] = r;
}

extern "C" void kernel_launch(void* const* d_in, const int* in_sizes, int n_in,
                              void* d_out, int out_size, void* d_ws, size_t ws_size,
                              hipStream_t stream) {
  const float* x  = (const float*)d_in[0];
  const float* Wr = (const float*)d_in[1];
  const float* br = (const float*)d_in[2];
  const float* W1 = (const float*)d_in[3];
  const float* b1 = (const float*)d_in[4];
  const float* W2 = (const float*)d_in[5];
  const float* b2 = (const float*)d_in[6];
  float* out = (float*)d_out;

  const int N = in_sizes[0] / D;                 // 32768
  const int cap = (int)(1.25f * (float)(N / E)); // 5120
  const int chunks = N / 256;                    // 128
  const int rblocks = N / (4 * RT);              // 1024 router blocks

  int* tokE = (int*)d_ws;                                    // N*2
  float* confPart = (float*)(tokE + (size_t)N * 2);          // rblocks
  int* chunkCnt = (int*)(confPart + rblocks);                // chunks*E
  int* chunkOff = chunkCnt + chunks * E;                     // chunks*E
  int* kept = chunkOff + chunks * E;                         // E
  int2* tokSlot = (int2*)(kept + E);                         // N int2
  int* expList = (int*)(tokSlot + N);                        // E*cap
  short* W1f = (short*)(expList + (size_t)E * cap);          // [E][128][64][8]
  short* W2f = W1f + (size_t)E * H * D;                      // [E][128][64][8]
  short* yscr = W2f + (size_t)E * H * D;                     // [E*cap][D] bf16
  short* xb = yscr + (size_t)E * cap * D;                    // [N][D] bf16 (optional)

  const size_t needed = (size_t)((char*)(xb + (size_t)N * D) - (char*)d_ws);
  const bool useXB = ws_size >= needed;

  k_swizzle<<<dim3(32, E), 256, 0, stream>>>(W1, W2, W1f, W2f);

  k_router<<<rblocks, 256, 0, stream>>>(x, Wr, br, tokE, confPart,
                                        useXB ? xb : nullptr);
  k_count<<<chunks, 256, 0, stream>>>(tokE, chunkCnt);
  k_scan<<<1, 512, 0, stream>>>(chunkCnt, confPart, chunkOff, kept,
                                out + (size_t)N * D, rblocks, cap, N);
  k_dispatch<<<chunks, 256, 0, stream>>>(tokE, chunkOff, expList, tokSlot, cap);

  const int tiles = (cap + BM - 1) / BM;        // 40
  dim3 g5(tiles, E);                            // 320 blocks x 8 waves
  if (useXB)
    k_expert_mfma<true><<<g5, 512, 0, stream>>>(xb, x, W1f, b1, W2f, b2,
                                                expList, kept, yscr, cap);
  else
    k_expert_mfma<false><<<g5, 512, 0, stream>>>(nullptr, x, W1f, b1, W2f, b2,
                                                 expList, kept, yscr, cap);

  k_combine<<<(N * D / 4) / 256, 256, 0, stream>>>(yscr, tokSlot, out);
}

// Round 18
// 107.147 us; speedup vs baseline: 1.1771x; 1.0037x over previous
//
#include <hip/hip_runtime.h>

#define D 512
#define E 8
#define H 128
#define BM 128   // tokens per expert block (8 waves: 2 row-groups x 4 col-groups)
#define HP 136   // LDS row stride in shorts (272B)
#define RT 4     // tokens per wave in router (8 waves/SIMD -> chains hidden)

typedef __attribute__((ext_vector_type(8))) short short8v;
typedef __attribute__((ext_vector_type(4))) short short4v;
typedef __attribute__((ext_vector_type(4))) float float4v;

__device__ inline short f2bf(float f) {
  union { float f; unsigned u; } v; v.f = f;
  unsigned r = v.u + 0x7fffu + ((v.u >> 16) & 1u);   // RNE
  return (short)(r >> 16);
}
__device__ inline float bf2f(short s) {
  union { unsigned u; float f; } v;
  v.u = ((unsigned)(unsigned short)s) << 16;
  return v.f;
}
__device__ inline void gload_lds4(const void* g, void* l) {
  __builtin_amdgcn_global_load_lds(
      (const __attribute__((address_space(1))) unsigned int*)g,
      (__attribute__((address_space(3))) unsigned int*)l, 4, 0, 0);
}

// ---------------- K0: swizzle weights into MFMA fragment-contiguous bf16 ----------------
// W1f[e][f=ks*8+t][lane][j]  (ks 0..15, t 0..7)
// W2f[e][f=t*4+ks][lane][j]  (t 0..31,  ks 0..3)   <- t-major
__global__ void k_swizzle(const float* __restrict__ W1, const float* __restrict__ W2,
                          short* __restrict__ W1f, short* __restrict__ W2f) {
  const int e = blockIdx.y;
  const int lane = threadIdx.x & 63;
  const int wv = threadIdx.x >> 6;
  const int r = lane & 15, g = lane >> 4;
  const int which = blockIdx.x >> 4;                 // 0: W1, 1: W2
  const int fbase = ((blockIdx.x & 15) * 4 + wv) * 2;
  if (which == 0) {
#pragma unroll
    for (int f = fbase; f < fbase + 2; ++f) {
      int ks = f >> 3, t = f & 7;
      const float* src = W1 + ((size_t)e * D + ks * 32 + g * 8) * H + t * 16 + r;
      short8v o;
#pragma unroll
      for (int j = 0; j < 8; ++j) o[j] = f2bf(src[(size_t)j * H]);
      *(short8v*)(W1f + (((size_t)e * 128 + f) * 64 + lane) * 8) = o;
    }
  } else {
#pragma unroll
    for (int f = fbase; f < fbase + 2; ++f) {
      int t = f >> 2, ks = f & 3;
      const float* src = W2 + ((size_t)e * H + ks * 32 + g * 8) * D + t * 16 + r;
      short8v o;
#pragma unroll
      for (int j = 0; j < 8; ++j) o[j] = f2bf(src[(size_t)j * D]);
      *(short8v*)(W2f + (((size_t)e * 128 + f) * 64 + lane) * 8) = o;
    }
  }
}

// ---------------- K1: router — one wave per RT tokens, fold-butterfly reduce (fp32 exact) ----------------
__global__ void k_router(const float* __restrict__ x, const float* __restrict__ Wr,
                         const float* __restrict__ br, int* __restrict__ tokE,
                         float* __restrict__ confPart, short* __restrict__ xb) {
  const int lane = threadIdx.x & 63;
  const int wave = threadIdx.x >> 6;
  const int tbase = (blockIdx.x * 4 + wave) * RT;

  float wr[8][8];
  const float4* wrp = reinterpret_cast<const float4*>(Wr) + lane * 16;
#pragma unroll
  for (int j = 0; j < 8; ++j) {
    float4 a = wrp[j * 2 + 0];
    float4 b = wrp[j * 2 + 1];
    wr[j][0] = a.x; wr[j][1] = a.y; wr[j][2] = a.z; wr[j][3] = a.w;
    wr[j][4] = b.x; wr[j][5] = b.y; wr[j][6] = b.z; wr[j][7] = b.w;
  }

  const int myE = ((lane & 1) << 2) | (lane & 2) | ((lane >> 2) & 1);
  const float brv = br[myE];

  float conf = 0.f;

#pragma unroll 2
  for (int tt = 0; tt < RT; ++tt) {
    const int token = tbase + tt;
    const float4* xp = reinterpret_cast<const float4*>(x + (size_t)token * D + lane * 8);
    float4 x0 = xp[0], x1 = xp[1];
    float xv[8] = {x0.x, x0.y, x0.z, x0.w, x1.x, x1.y, x1.z, x1.w};

    if (xb) {
      short8v p;
#pragma unroll
      for (int j = 0; j < 8; ++j) p[j] = f2bf(xv[j]);
      *(short8v*)(xb + (size_t)token * D + lane * 8) = p;
    }

    float v[8] = {0, 0, 0, 0, 0, 0, 0, 0};
#pragma unroll
    for (int j = 0; j < 8; ++j)
#pragma unroll
      for (int e = 0; e < E; ++e)
        v[e] += xv[j] * wr[j][e];

#pragma unroll
    for (int i = 0; i < 4; ++i) {
      float a = v[i] + __shfl_xor(v[i], 1, 64);
      float b = v[i + 4] + __shfl_xor(v[i + 4], 1, 64);
      v[i] = (lane & 1) ? b : a;
    }
#pragma unroll
    for (int i = 0; i < 2; ++i) {
      float a = v[i] + __shfl_xor(v[i], 2, 64);
      float b = v[i + 2] + __shfl_xor(v[i + 2], 2, 64);
      v[i] = (lane & 2) ? b : a;
    }
    {
      float a = v[0] + __shfl_xor(v[0], 4, 64);
      float b = v[1] + __shfl_xor(v[1], 4, 64);
      v[0] = (lane & 4) ? b : a;
    }
    v[0] += __shfl_xor(v[0], 8, 64);
    v[0] += __shfl_xor(v[0], 16, 64);
    v[0] += __shfl_xor(v[0], 32, 64);

    const float logit = v[0] + brv;

    float m1 = logit; int i1 = myE;
#pragma unroll
    for (int m = 1; m <= 4; m <<= 1) {
      float om = __shfl_xor(m1, m, 64);
      int oi = __shfl_xor(i1, m, 64);
      bool take = (om > m1) || (om == m1 && oi < i1);
      m1 = take ? om : m1;
      i1 = take ? oi : i1;
    }
    float s1 = (myE == i1) ? -1e30f : logit; int j1 = myE;
#pragma unroll
    for (int m = 1; m <= 4; m <<= 1) {
      float om = __shfl_xor(s1, m, 64);
      int oi = __shfl_xor(j1, m, 64);
      bool take = (om > s1) || (om == s1 && oi < j1);
      s1 = take ? om : s1;
      j1 = take ? oi : j1;
    }

    if (lane == 0) {
      tokE[token * 2 + 0] = i1;
      tokE[token * 2 + 1] = j1;
    }
    conf += m1;
  }

  __shared__ float cf[4];
  if (lane == 0) cf[wave] = conf;
  __syncthreads();
  if (threadIdx.x == 0) confPart[blockIdx.x] = cf[0] + cf[1] + cf[2] + cf[3];
}

// ---------------- K2: per-chunk (256 tokens) expert counts ----------------
__global__ void k_count(const int* __restrict__ tokE, int* __restrict__ chunkCnt) {
  __shared__ int c[E];
  if (threadIdx.x < E) c[threadIdx.x] = 0;
  __syncthreads();
  int token = blockIdx.x * 256 + threadIdx.x;
  atomicAdd(&c[tokE[token * 2 + 0]], 1);
  atomicAdd(&c[tokE[token * 2 + 1]], 1);
  __syncthreads();
  if (threadIdx.x < E) chunkCnt[blockIdx.x * E + threadIdx.x] = c[threadIdx.x];
}

// ---------------- K3: wave-parallel scan + stats ----------------
__global__ void k_scan(const int* __restrict__ chunkCnt, const float* __restrict__ confPart,
                       int* __restrict__ chunkOff, int* __restrict__ kept,
                       float* __restrict__ outTail, int nConf, int cap, int nTok) {
  const int lane = threadIdx.x & 63;
  const int e = threadIdx.x >> 6;
  __shared__ int keptS[E];

  int v0 = chunkCnt[lane * E + e];
  int v1 = chunkCnt[(64 + lane) * E + e];
  int s0 = v0, s1 = v1;
#pragma unroll
  for (int off = 1; off < 64; off <<= 1) {
    int t0 = __shfl_up(s0, off, 64);
    int t1 = __shfl_up(s1, off, 64);
    if (lane >= off) { s0 += t0; s1 += t1; }
  }
  int tot0 = __shfl(s0, 63, 64);
  int total = tot0 + __shfl(s1, 63, 64);
  chunkOff[lane * E + e] = s0 - v0;
  chunkOff[(64 + lane) * E + e] = tot0 + s1 - v1;
  if (lane == 0) {
    int k = min(total, cap);
    kept[e] = k;
    keptS[e] = k;
  }

  __shared__ float s[512];
  float a = 0.f;
  for (int i = threadIdx.x; i < nConf; i += 512) a += confPart[i];
  s[threadIdx.x] = a;
  __syncthreads();
  for (int st = 256; st > 0; st >>= 1) {
    if (threadIdx.x < st) s[threadIdx.x] += s[threadIdx.x + st];
    __syncthreads();
  }
  if (threadIdx.x == 0) {
    float tot = 0.f, ld[E];
    for (int i = 0; i < E; ++i) { ld[i] = (float)keptS[i]; tot += ld[i]; }
    float denom = tot + 1e-8f;
    float loss = 0.f;
    for (int i = 0; i < E; ++i) {
      float dist = ld[i] / denom;
      loss += dist * logf(dist + 1e-8f);
      outTail[1 + i] = dist;
    }
    outTail[0] = loss;
    outTail[1 + E] = s[0] / (float)nTok;
  }
}

// ---------------- K4: rank assignment + dispatch lists + token->slot map ----------------
__global__ void k_dispatch(const int* __restrict__ tokE, const int* __restrict__ chunkOff,
                           int* __restrict__ expList, int2* __restrict__ tokSlot, int cap) {
  const int lane = threadIdx.x & 63;
  const int wave = threadIdx.x >> 6;
  const int token = blockIdx.x * 256 + threadIdx.x;
  const int e0 = tokE[token * 2 + 0];
  const int e1 = tokE[token * 2 + 1];
  __shared__ int wcnt[4][E];
  unsigned long long lt = (lane == 63) ? 0x7fffffffffffffffull : ((1ull << lane) - 1ull);
  int r0 = 0, r1 = 0;
#pragma unroll
  for (int e = 0; e < E; ++e) {
    unsigned long long b0 = __ballot(e0 == e);
    unsigned long long b1 = __ballot(e1 == e);
    unsigned long long m = b0 | b1;
    if (e0 == e) r0 = __popcll(m & lt);
    if (e1 == e) r1 = __popcll(m & lt);
    if (lane == 0) wcnt[wave][e] = __popcll(m);
  }
  __syncthreads();
  int base0 = chunkOff[blockIdx.x * E + e0];
  int base1 = chunkOff[blockIdx.x * E + e1];
  for (int w = 0; w < wave; ++w) {
    base0 += wcnt[w][e0];
    base1 += wcnt[w][e1];
  }
  int g0 = base0 + r0;
  int g1 = base1 + r1;
  if (g0 < cap) expList[e0 * cap + g0] = token;
  if (g1 < cap) expList[e1 * cap + g1] = token;
  tokSlot[token] = make_int2(g0 < cap ? e0 * cap + g0 : -1,
                             g1 < cap ? e1 * cap + g1 : -1);
}

// ---------------- K5: per-expert FFN via MFMA (r15 structure) ----------------
// 8 waves = (rowg 0..1) x (ng 0..3). L1: wave computes 4 row-tiles x 2 h-tiles
// (each W1 frag feeds 4 MFMAs). L2: 2 passes of 2 row-tiles x 8 d-tiles.
template <bool USE_XB>
__global__ __launch_bounds__(512, 1) void k_expert_mfma(
    const short* __restrict__ xb, const float* __restrict__ x,
    const short* __restrict__ W1f, const float* __restrict__ b1,
    const short* __restrict__ W2f, const float* __restrict__ b2,
    const int* __restrict__ expList, const int* __restrict__ kept,
    short* __restrict__ yscr, int cap) {
  const int e = blockIdx.y;
  const int cnt = kept[e];
  const int t0 = blockIdx.x * BM;
  if (t0 >= cnt) return;
  const int lane = threadIdx.x & 63;
  const int wave = threadIdx.x >> 6;   // 0..7
  const int rowg = wave >> 2;          // 0..1 -> rows [rowg*64, rowg*64+64)
  const int ng = wave & 3;             // 0..3 -> output-column quarter
  const int n15 = lane & 15;
  const int grp = lane >> 4;
  const int kg = grp * 8;

  __shared__ int toks[BM];
  __shared__ short sbuf[2 * BM * HP];   // x phase double-buffer; buf0 reused as hs

  if (threadIdx.x < BM) {
    int idx = min(t0 + (int)threadIdx.x, cnt - 1);
    toks[threadIdx.x] = expList[e * cap + idx];
  }
  __syncthreads();

  const short* w1 = W1f + (size_t)e * (128 * 512);
  const short* w2 = W2f + (size_t)e * (128 * 512);

  float4v acc[4][2];
#pragma unroll
  for (int r = 0; r < 4; ++r)
#pragma unroll
    for (int t = 0; t < 2; ++t)
      acc[r][t] = (float4v){0.f, 0.f, 0.f, 0.f};

  if (USE_XB) {
    // stage phase p: token row bytes [p*256, +256) -> sbuf[p&1][ti][..]; 16 rows/wave
    auto stageX = [&](int p) {
#pragma unroll
      for (int j = 0; j < 16; ++j) {
        int ti = wave * 16 + j;
        const short* src = xb + (size_t)toks[ti] * D + p * 128 + lane * 2;
        short* dst = &sbuf[(p & 1) * (BM * HP) + ti * HP];
        gload_lds4(src, dst);
      }
    };
    stageX(0);
    __syncthreads();
#pragma unroll
    for (int p = 0; p < 4; ++p) {
      if (p < 3) stageX(p + 1);
#pragma unroll
      for (int ksl = 0; ksl < 4; ++ksl) {
        const int ks = p * 4 + ksl;
        const short* sb = &sbuf[(p & 1) * (BM * HP)];
        short8v xf[4];
#pragma unroll
        for (int r = 0; r < 4; ++r)
          xf[r] = *(const short8v*)&sb[(rowg * 64 + r * 16 + n15) * HP + ksl * 32 + kg];
        short8v wf[2];
#pragma unroll
        for (int t = 0; t < 2; ++t)
          wf[t] = *(const short8v*)(w1 + (size_t)(ks * 8 + ng * 2 + t) * 512 + lane * 8);
#pragma unroll
        for (int t = 0; t < 2; ++t)
#pragma unroll
          for (int r = 0; r < 4; ++r)
            acc[r][t] = __builtin_amdgcn_mfma_f32_16x16x32_bf16(wf[t], xf[r], acc[r][t], 0, 0, 0);
      }
      __syncthreads();
    }
  } else {
    // fallback: per-lane gather from fp32 x (correctness path)
#pragma unroll 1
    for (int ks = 0; ks < 16; ++ks) {
      short8v xf[4];
#pragma unroll
      for (int r = 0; r < 4; ++r) {
        const float* xr = x + (size_t)toks[rowg * 64 + r * 16 + n15] * D + kg + ks * 32;
        float4 a0 = *(const float4*)(xr);
        float4 a1 = *(const float4*)(xr + 4);
        short8v f;
        f[0] = f2bf(a0.x); f[1] = f2bf(a0.y); f[2] = f2bf(a0.z); f[3] = f2bf(a0.w);
        f[4] = f2bf(a1.x); f[5] = f2bf(a1.y); f[6] = f2bf(a1.z); f[7] = f2bf(a1.w);
        xf[r] = f;
      }
      short8v wf[2];
#pragma unroll
      for (int t = 0; t < 2; ++t)
        wf[t] = *(const short8v*)(w1 + (size_t)(ks * 8 + ng * 2 + t) * 512 + lane * 8);
#pragma unroll
      for (int t = 0; t < 2; ++t)
#pragma unroll
        for (int r = 0; r < 4; ++r)
          acc[r][t] = __builtin_amdgcn_mfma_f32_16x16x32_bf16(wf[t], xf[r], acc[r][t], 0, 0, 0);
    }
    __syncthreads();
  }

  // ---- h = relu(acc + b1) -> sbuf buffer0; wave writes 4 row-tiles x 2 col-tiles ----
#pragma unroll
  for (int t = 0; t < 2; ++t) {
    int tg = ng * 2 + t;
    float4 bb = *(const float4*)(b1 + e * H + tg * 16 + grp * 4);
#pragma unroll
    for (int r = 0; r < 4; ++r) {
      short4v p;
      p[0] = f2bf(fmaxf(acc[r][t][0] + bb.x, 0.f));
      p[1] = f2bf(fmaxf(acc[r][t][1] + bb.y, 0.f));
      p[2] = f2bf(fmaxf(acc[r][t][2] + bb.z, 0.f));
      p[3] = f2bf(fmaxf(acc[r][t][3] + bb.w, 0.f));
      *(short4v*)(&sbuf[(rowg * 64 + r * 16 + n15) * HP + tg * 16 + grp * 4]) = p;
    }
  }
  __syncthreads();

  // ---- layer 2: 2 passes, each = 2 row-tiles x 8 d-tiles (ng split of 32) ----
#pragma unroll
  for (int rp = 0; rp < 2; ++rp) {
    const int rbase = rowg * 64 + rp * 32;
    short8v a4[2][4];
#pragma unroll
    for (int ri = 0; ri < 2; ++ri)
#pragma unroll
      for (int ks = 0; ks < 4; ++ks)
        a4[ri][ks] = *(const short8v*)(&sbuf[(rbase + ri * 16 + n15) * HP + ks * 32 + kg]);

    short* yrow0 = yscr + ((size_t)(e * cap + t0 + rbase + n15)) * D;
    short* yrow1 = yrow0 + (size_t)16 * D;
#pragma unroll 4
    for (int tt = 0; tt < 8; ++tt) {
      const int t = ng * 8 + tt;
      short8v wf[4];
#pragma unroll
      for (int ks = 0; ks < 4; ++ks)
        wf[ks] = *(const short8v*)(w2 + (size_t)(t * 4 + ks) * 512 + lane * 8);
      float4v y0 = (float4v){0.f, 0.f, 0.f, 0.f};
      float4v y1 = (float4v){0.f, 0.f, 0.f, 0.f};
#pragma unroll
      for (int ks = 0; ks < 4; ++ks) {
        y0 = __builtin_amdgcn_mfma_f32_16x16x32_bf16(wf[ks], a4[0][ks], y0, 0, 0, 0);
        y1 = __builtin_amdgcn_mfma_f32_16x16x32_bf16(wf[ks], a4[1][ks], y1, 0, 0, 0);
      }
      float4 bb = *(const float4*)(b2 + e * D + t * 16 + grp * 4);
      short4v p0, p1;
      p0[0] = f2bf(y0[0] + bb.x);
      p0[1] = f2bf(y0[1] + bb.y);
      p0[2] = f2bf(y0[2] + bb.z);
      p0[3] = f2bf(y0[3] + bb.w);
      p1[0] = f2bf(y1[0] + bb.x);
      p1[1] = f2bf(y1[1] + bb.y);
      p1[2] = f2bf(y1[2] + bb.z);
      p1[3] = f2bf(y1[3] + bb.w);
      *(short4v*)(yrow0 + t * 16 + grp * 4) = p0;
      *(short4v*)(yrow1 + t * 16 + grp * 4) = p1;
    }
  }
}

// ---------------- K6: combine — out[token] = sum of kept slots (or 0) ----------------
__global__ void k_combine(const short* __restrict__ yscr, const int2* __restrict__ tokSlot,
                          float* __restrict__ out) {
  const int idx = blockIdx.x * 256 + threadIdx.x;
  const int token = idx >> 7;
  const int c4 = idx & 127;
  int2 sl = tokSlot[token];
  float4 r = make_float4(0.f, 0.f, 0.f, 0.f);
  if (sl.x >= 0) {
    short4v y = *(const short4v*)(yscr + (size_t)sl.x * D + c4 * 4);
    r.x += bf2f(y[0]); r.y += bf2f(y[1]); r.z += bf2f(y[2]); r.w += bf2f(y[3]);
  }
  if (sl.y >= 0) {
    short4v y = *(const short4v*)(yscr + (size_t)sl.y * D + c4 * 4);
    r.x += bf2f(y[0]); r.y += bf2f(y[1]); r.z += bf2f(y[2]); r.w += bf2f(y[3]);
  }
  reinterpret_cast<float4*>(out)[idx] = r;
}

extern "C" void kernel_launch(void* const* d_in, const int* in_sizes, int n_in,
                              void* d_out, int out_size, void* d_ws, size_t ws_size,
                              hipStream_t stream) {
  const float* x  = (const float*)d_in[0];
  const float* Wr = (const float*)d_in[1];
  const float* br = (const float*)d_in[2];
  const float* W1 = (const float*)d_in[3];
  const float* b1 = (const float*)d_in[4];
  const float* W2 = (const float*)d_in[5];
  const float* b2 = (const float*)d_in[6];
  float* out = (float*)d_out;

  const int N = in_sizes[0] / D;                 // 32768
  const int cap = (int)(1.25f * (float)(N / E)); // 5120
  const int chunks = N / 256;                    // 128
  const int rblocks = N / (4 * RT);              // 2048 router blocks

  int* tokE = (int*)d_ws;                                    // N*2
  float* confPart = (float*)(tokE + (size_t)N * 2);          // rblocks
  int* chunkCnt = (int*)(confPart + rblocks);                // chunks*E
  int* chunkOff = chunkCnt + chunks * E;                     // chunks*E
  int* kept = chunkOff + chunks * E;                         // E
  int2* tokSlot = (int2*)(kept + E);                         // N int2
  int* expList = (int*)(tokSlot + N);                        // E*cap
  short* W1f = (short*)(expList + (size_t)E * cap);          // [E][128][64][8]
  short* W2f = W1f + (size_t)E * H * D;                      // [E][128][64][8]
  short* yscr = W2f + (size_t)E * H * D;                     // [E*cap][D] bf16
  short* xb = yscr + (size_t)E * cap * D;                    // [N][D] bf16 (optional)

  const size_t needed = (size_t)((char*)(xb + (size_t)N * D) - (char*)d_ws);
  const bool useXB = ws_size >= needed;

  k_swizzle<<<dim3(32, E), 256, 0, stream>>>(W1, W2, W1f, W2f);

  k_router<<<rblocks, 256, 0, stream>>>(x, Wr, br, tokE, confPart,
                                        useXB ? xb : nullptr);
  k_count<<<chunks, 256, 0, stream>>>(tokE, chunkCnt);
  k_scan<<<1, 512, 0, stream>>>(chunkCnt, confPart, chunkOff, kept,
                                out + (size_t)N * D, rblocks, cap, N);
  k_dispatch<<<chunks, 256, 0, stream>>>(tokE, chunkOff, expList, tokSlot, cap);

  const int tiles = (cap + BM - 1) / BM;        // 40
  dim3 g5(tiles, E);                            // 320 blocks x 8 waves
  if (useXB)
    k_expert_mfma<true><<<g5, 512, 0, stream>>>(xb, x, W1f, b1, W2f, b2,
                                                expList, kept, yscr, cap);
  else
    k_expert_mfma<false><<<g5, 512, 0, stream>>>(nullptr, x, W1f, b1, W2f, b2,
                                                 expList, kept, yscr, cap);

  k_combine<<<(N * D / 4) / 256, 256, 0, stream>>>(yscr, tokSlot, out);
}

// Round 19
// 105.506 us; speedup vs baseline: 1.1954x; 1.0156x over previous
//
#include <hip/hip_runtime.h>

#define D 512
#define E 8
#define H 128
#define BM 128   // tokens per expert block (8 waves: 2 row-groups x 4 col-groups)
#define HP 136   // LDS row stride in shorts (272B)
#define RT 8     // tokens per wave in router

typedef __attribute__((ext_vector_type(8))) short short8v;
typedef __attribute__((ext_vector_type(4))) short short4v;
typedef __attribute__((ext_vector_type(4))) float float4v;

__device__ inline short f2bf(float f) {
  union { float f; unsigned u; } v; v.f = f;
  unsigned r = v.u + 0x7fffu + ((v.u >> 16) & 1u);   // RNE
  return (short)(r >> 16);
}
__device__ inline float bf2f(short s) {
  union { unsigned u; float f; } v;
  v.u = ((unsigned)(unsigned short)s) << 16;
  return v.f;
}
__device__ inline void gload_lds4(const void* g, void* l) {
  __builtin_amdgcn_global_load_lds(
      (const __attribute__((address_space(1))) unsigned int*)g,
      (__attribute__((address_space(3))) unsigned int*)l, 4, 0, 0);
}

// ---------------- K0: swizzle weights into MFMA fragment-contiguous bf16 ----------------
// W1f[e][f=ks*8+t][lane][j]  (ks 0..15, t 0..7)
// W2f[e][f=t*4+ks][lane][j]  (t 0..31,  ks 0..3)   <- t-major
__global__ void k_swizzle(const float* __restrict__ W1, const float* __restrict__ W2,
                          short* __restrict__ W1f, short* __restrict__ W2f) {
  const int e = blockIdx.y;
  const int lane = threadIdx.x & 63;
  const int wv = threadIdx.x >> 6;
  const int r = lane & 15, g = lane >> 4;
  const int which = blockIdx.x >> 4;                 // 0: W1, 1: W2
  const int fbase = ((blockIdx.x & 15) * 4 + wv) * 2;
  if (which == 0) {
#pragma unroll
    for (int f = fbase; f < fbase + 2; ++f) {
      int ks = f >> 3, t = f & 7;
      const float* src = W1 + ((size_t)e * D + ks * 32 + g * 8) * H + t * 16 + r;
      short8v o;
#pragma unroll
      for (int j = 0; j < 8; ++j) o[j] = f2bf(src[(size_t)j * H]);
      *(short8v*)(W1f + (((size_t)e * 128 + f) * 64 + lane) * 8) = o;
    }
  } else {
#pragma unroll
    for (int f = fbase; f < fbase + 2; ++f) {
      int t = f >> 2, ks = f & 3;
      const float* src = W2 + ((size_t)e * H + ks * 32 + g * 8) * D + t * 16 + r;
      short8v o;
#pragma unroll
      for (int j = 0; j < 8; ++j) o[j] = f2bf(src[(size_t)j * D]);
      *(short8v*)(W2f + (((size_t)e * 128 + f) * 64 + lane) * 8) = o;
    }
  }
}

// ---------------- K1: router — one wave per RT tokens, fold-butterfly reduce (fp32 exact) ----------------
__global__ void k_router(const float* __restrict__ x, const float* __restrict__ Wr,
                         const float* __restrict__ br, int* __restrict__ tokE,
                         float* __restrict__ confPart, short* __restrict__ xb) {
  const int lane = threadIdx.x & 63;
  const int wave = threadIdx.x >> 6;
  const int tbase = (blockIdx.x * 4 + wave) * RT;

  float wr[8][8];
  const float4* wrp = reinterpret_cast<const float4*>(Wr) + lane * 16;
#pragma unroll
  for (int j = 0; j < 8; ++j) {
    float4 a = wrp[j * 2 + 0];
    float4 b = wrp[j * 2 + 1];
    wr[j][0] = a.x; wr[j][1] = a.y; wr[j][2] = a.z; wr[j][3] = a.w;
    wr[j][4] = b.x; wr[j][5] = b.y; wr[j][6] = b.z; wr[j][7] = b.w;
  }

  const int myE = ((lane & 1) << 2) | (lane & 2) | ((lane >> 2) & 1);
  const float brv = br[myE];

  float conf = 0.f;

#pragma unroll 2
  for (int tt = 0; tt < RT; ++tt) {
    const int token = tbase + tt;
    const float4* xp = reinterpret_cast<const float4*>(x + (size_t)token * D + lane * 8);
    float4 x0 = xp[0], x1 = xp[1];
    float xv[8] = {x0.x, x0.y, x0.z, x0.w, x1.x, x1.y, x1.z, x1.w};

    if (xb) {
      short8v p;
#pragma unroll
      for (int j = 0; j < 8; ++j) p[j] = f2bf(xv[j]);
      *(short8v*)(xb + (size_t)token * D + lane * 8) = p;
    }

    float v[8] = {0, 0, 0, 0, 0, 0, 0, 0};
#pragma unroll
    for (int j = 0; j < 8; ++j)
#pragma unroll
      for (int e = 0; e < E; ++e)
        v[e] += xv[j] * wr[j][e];

#pragma unroll
    for (int i = 0; i < 4; ++i) {
      float a = v[i] + __shfl_xor(v[i], 1, 64);
      float b = v[i + 4] + __shfl_xor(v[i + 4], 1, 64);
      v[i] = (lane & 1) ? b : a;
    }
#pragma unroll
    for (int i = 0; i < 2; ++i) {
      float a = v[i] + __shfl_xor(v[i], 2, 64);
      float b = v[i + 2] + __shfl_xor(v[i + 2], 2, 64);
      v[i] = (lane & 2) ? b : a;
    }
    {
      float a = v[0] + __shfl_xor(v[0], 4, 64);
      float b = v[1] + __shfl_xor(v[1], 4, 64);
      v[0] = (lane & 4) ? b : a;
    }
    v[0] += __shfl_xor(v[0], 8, 64);
    v[0] += __shfl_xor(v[0], 16, 64);
    v[0] += __shfl_xor(v[0], 32, 64);

    const float logit = v[0] + brv;

    float m1 = logit; int i1 = myE;
#pragma unroll
    for (int m = 1; m <= 4; m <<= 1) {
      float om = __shfl_xor(m1, m, 64);
      int oi = __shfl_xor(i1, m, 64);
      bool take = (om > m1) || (om == m1 && oi < i1);
      m1 = take ? om : m1;
      i1 = take ? oi : i1;
    }
    float s1 = (myE == i1) ? -1e30f : logit; int j1 = myE;
#pragma unroll
    for (int m = 1; m <= 4; m <<= 1) {
      float om = __shfl_xor(s1, m, 64);
      int oi = __shfl_xor(j1, m, 64);
      bool take = (om > s1) || (om == s1 && oi < j1);
      s1 = take ? om : s1;
      j1 = take ? oi : j1;
    }

    if (lane == 0) {
      tokE[token * 2 + 0] = i1;
      tokE[token * 2 + 1] = j1;
    }
    conf += m1;
  }

  __shared__ float cf[4];
  if (lane == 0) cf[wave] = conf;
  __syncthreads();
  if (threadIdx.x == 0) confPart[blockIdx.x] = cf[0] + cf[1] + cf[2] + cf[3];
}

// ---------------- K2: per-chunk (256 tokens) expert counts ----------------
__global__ void k_count(const int* __restrict__ tokE, int* __restrict__ chunkCnt) {
  __shared__ int c[E];
  if (threadIdx.x < E) c[threadIdx.x] = 0;
  __syncthreads();
  int token = blockIdx.x * 256 + threadIdx.x;
  atomicAdd(&c[tokE[token * 2 + 0]], 1);
  atomicAdd(&c[tokE[token * 2 + 1]], 1);
  __syncthreads();
  if (threadIdx.x < E) chunkCnt[blockIdx.x * E + threadIdx.x] = c[threadIdx.x];
}

// ---------------- K3: wave-parallel scan + stats ----------------
__global__ void k_scan(const int* __restrict__ chunkCnt, const float* __restrict__ confPart,
                       int* __restrict__ chunkOff, int* __restrict__ kept,
                       float* __restrict__ outTail, int nConf, int cap, int nTok) {
  const int lane = threadIdx.x & 63;
  const int e = threadIdx.x >> 6;
  __shared__ int keptS[E];

  int v0 = chunkCnt[lane * E + e];
  int v1 = chunkCnt[(64 + lane) * E + e];
  int s0 = v0, s1 = v1;
#pragma unroll
  for (int off = 1; off < 64; off <<= 1) {
    int t0 = __shfl_up(s0, off, 64);
    int t1 = __shfl_up(s1, off, 64);
    if (lane >= off) { s0 += t0; s1 += t1; }
  }
  int tot0 = __shfl(s0, 63, 64);
  int total = tot0 + __shfl(s1, 63, 64);
  chunkOff[lane * E + e] = s0 - v0;
  chunkOff[(64 + lane) * E + e] = tot0 + s1 - v1;
  if (lane == 0) {
    int k = min(total, cap);
    kept[e] = k;
    keptS[e] = k;
  }

  __shared__ float s[512];
  float a = 0.f;
  for (int i = threadIdx.x; i < nConf; i += 512) a += confPart[i];
  s[threadIdx.x] = a;
  __syncthreads();
  for (int st = 256; st > 0; st >>= 1) {
    if (threadIdx.x < st) s[threadIdx.x] += s[threadIdx.x + st];
    __syncthreads();
  }
  if (threadIdx.x == 0) {
    float tot = 0.f, ld[E];
    for (int i = 0; i < E; ++i) { ld[i] = (float)keptS[i]; tot += ld[i]; }
    float denom = tot + 1e-8f;
    float loss = 0.f;
    for (int i = 0; i < E; ++i) {
      float dist = ld[i] / denom;
      loss += dist * logf(dist + 1e-8f);
      outTail[1 + i] = dist;
    }
    outTail[0] = loss;
    outTail[1 + E] = s[0] / (float)nTok;
  }
}

// ---------------- K4: rank assignment + dispatch lists + token->slot map ----------------
__global__ void k_dispatch(const int* __restrict__ tokE, const int* __restrict__ chunkOff,
                           int* __restrict__ expList, int2* __restrict__ tokSlot, int cap) {
  const int lane = threadIdx.x & 63;
  const int wave = threadIdx.x >> 6;
  const int token = blockIdx.x * 256 + threadIdx.x;
  const int e0 = tokE[token * 2 + 0];
  const int e1 = tokE[token * 2 + 1];
  __shared__ int wcnt[4][E];
  unsigned long long lt = (lane == 63) ? 0x7fffffffffffffffull : ((1ull << lane) - 1ull);
  int r0 = 0, r1 = 0;
#pragma unroll
  for (int e = 0; e < E; ++e) {
    unsigned long long b0 = __ballot(e0 == e);
    unsigned long long b1 = __ballot(e1 == e);
    unsigned long long m = b0 | b1;
    if (e0 == e) r0 = __popcll(m & lt);
    if (e1 == e) r1 = __popcll(m & lt);
    if (lane == 0) wcnt[wave][e] = __popcll(m);
  }
  __syncthreads();
  int base0 = chunkOff[blockIdx.x * E + e0];
  int base1 = chunkOff[blockIdx.x * E + e1];
  for (int w = 0; w < wave; ++w) {
    base0 += wcnt[w][e0];
    base1 += wcnt[w][e1];
  }
  int g0 = base0 + r0;
  int g1 = base1 + r1;
  if (g0 < cap) expList[e0 * cap + g0] = token;
  if (g1 < cap) expList[e1 * cap + g1] = token;
  tokSlot[token] = make_int2(g0 < cap ? e0 * cap + g0 : -1,
                             g1 < cap ? e1 * cap + g1 : -1);
}

// ---------------- K5: per-expert FFN via MFMA, XCD-pinned (grid E,tiles; no NT) ----------------
// 8 waves = (rowg 0..1) x (ng 0..3). L1: wave computes 4 row-tiles x 2 h-tiles
// (each W1 frag feeds 4 MFMAs). L2: 2 passes of 2 row-tiles x 8 d-tiles.
template <bool USE_XB>
__global__ __launch_bounds__(512, 1) void k_expert_mfma(
    const short* __restrict__ xb, const float* __restrict__ x,
    const short* __restrict__ W1f, const float* __restrict__ b1,
    const short* __restrict__ W2f, const float* __restrict__ b2,
    const int* __restrict__ expList, const int* __restrict__ kept,
    short* __restrict__ yscr, int cap) {
  const int e = blockIdx.x;                 // linear bid % 8 == e -> XCD pin
  const int cnt = kept[e];
  const int t0 = blockIdx.y * BM;
  if (t0 >= cnt) return;
  const int lane = threadIdx.x & 63;
  const int wave = threadIdx.x >> 6;   // 0..7
  const int rowg = wave >> 2;          // 0..1 -> rows [rowg*64, rowg*64+64)
  const int ng = wave & 3;             // 0..3 -> output-column quarter
  const int n15 = lane & 15;
  const int grp = lane >> 4;
  const int kg = grp * 8;

  __shared__ int toks[BM];
  __shared__ short sbuf[2 * BM * HP];   // x phase double-buffer; buf0 reused as hs

  if (threadIdx.x < BM) {
    int idx = min(t0 + (int)threadIdx.x, cnt - 1);
    toks[threadIdx.x] = expList[e * cap + idx];
  }
  __syncthreads();

  const short* w1 = W1f + (size_t)e * (128 * 512);
  const short* w2 = W2f + (size_t)e * (128 * 512);

  float4v acc[4][2];
#pragma unroll
  for (int r = 0; r < 4; ++r)
#pragma unroll
    for (int t = 0; t < 2; ++t)
      acc[r][t] = (float4v){0.f, 0.f, 0.f, 0.f};

  if (USE_XB) {
    // stage phase p: token row bytes [p*256, +256) -> sbuf[p&1][ti][..]; 16 rows/wave
    auto stageX = [&](int p) {
#pragma unroll
      for (int j = 0; j < 16; ++j) {
        int ti = wave * 16 + j;
        const short* src = xb + (size_t)toks[ti] * D + p * 128 + lane * 2;
        short* dst = &sbuf[(p & 1) * (BM * HP) + ti * HP];
        gload_lds4(src, dst);
      }
    };
    stageX(0);
    __syncthreads();
#pragma unroll
    for (int p = 0; p < 4; ++p) {
      if (p < 3) stageX(p + 1);
#pragma unroll
      for (int ksl = 0; ksl < 4; ++ksl) {
        const int ks = p * 4 + ksl;
        const short* sb = &sbuf[(p & 1) * (BM * HP)];
        short8v xf[4];
#pragma unroll
        for (int r = 0; r < 4; ++r)
          xf[r] = *(const short8v*)&sb[(rowg * 64 + r * 16 + n15) * HP + ksl * 32 + kg];
        short8v wf[2];
#pragma unroll
        for (int t = 0; t < 2; ++t)
          wf[t] = *(const short8v*)(w1 + (size_t)(ks * 8 + ng * 2 + t) * 512 + lane * 8);
#pragma unroll
        for (int t = 0; t < 2; ++t)
#pragma unroll
          for (int r = 0; r < 4; ++r)
            acc[r][t] = __builtin_amdgcn_mfma_f32_16x16x32_bf16(wf[t], xf[r], acc[r][t], 0, 0, 0);
      }
      __syncthreads();
    }
  } else {
    // fallback: per-lane gather from fp32 x (correctness path)
#pragma unroll 1
    for (int ks = 0; ks < 16; ++ks) {
      short8v xf[4];
#pragma unroll
      for (int r = 0; r < 4; ++r) {
        const float* xr = x + (size_t)toks[rowg * 64 + r * 16 + n15] * D + kg + ks * 32;
        float4 a0 = *(const float4*)(xr);
        float4 a1 = *(const float4*)(xr + 4);
        short8v f;
        f[0] = f2bf(a0.x); f[1] = f2bf(a0.y); f[2] = f2bf(a0.z); f[3] = f2bf(a0.w);
        f[4] = f2bf(a1.x); f[5] = f2bf(a1.y); f[6] = f2bf(a1.z); f[7] = f2bf(a1.w);
        xf[r] = f;
      }
      short8v wf[2];
#pragma unroll
      for (int t = 0; t < 2; ++t)
        wf[t] = *(const short8v*)(w1 + (size_t)(ks * 8 + ng * 2 + t) * 512 + lane * 8);
#pragma unroll
      for (int t = 0; t < 2; ++t)
#pragma unroll
        for (int r = 0; r < 4; ++r)
          acc[r][t] = __builtin_amdgcn_mfma_f32_16x16x32_bf16(wf[t], xf[r], acc[r][t], 0, 0, 0);
    }
    __syncthreads();
  }

  // ---- h = relu(acc + b1) -> sbuf buffer0; wave writes 4 row-tiles x 2 col-tiles ----
#pragma unroll
  for (int t = 0; t < 2; ++t) {
    int tg = ng * 2 + t;
    float4 bb = *(const float4*)(b1 + e * H + tg * 16 + grp * 4);
#pragma unroll
    for (int r = 0; r < 4; ++r) {
      short4v p;
      p[0] = f2bf(fmaxf(acc[r][t][0] + bb.x, 0.f));
      p[1] = f2bf(fmaxf(acc[r][t][1] + bb.y, 0.f));
      p[2] = f2bf(fmaxf(acc[r][t][2] + bb.z, 0.f));
      p[3] = f2bf(fmaxf(acc[r][t][3] + bb.w, 0.f));
      *(short4v*)(&sbuf[(rowg * 64 + r * 16 + n15) * HP + tg * 16 + grp * 4]) = p;
    }
  }
  __syncthreads();

  // ---- layer 2: 2 passes, each = 2 row-tiles x 8 d-tiles (ng split of 32) ----
#pragma unroll
  for (int rp = 0; rp < 2; ++rp) {
    const int rbase = rowg * 64 + rp * 32;
    short8v a4[2][4];
#pragma unroll
    for (int ri = 0; ri < 2; ++ri)
#pragma unroll
      for (int ks = 0; ks < 4; ++ks)
        a4[ri][ks] = *(const short8v*)(&sbuf[(rbase + ri * 16 + n15) * HP + ks * 32 + kg]);

    short* yrow0 = yscr + ((size_t)(e * cap + t0 + rbase + n15)) * D;
    short* yrow1 = yrow0 + (size_t)16 * D;
#pragma unroll 4
    for (int tt = 0; tt < 8; ++tt) {
      const int t = ng * 8 + tt;
      short8v wf[4];
#pragma unroll
      for (int ks = 0; ks < 4; ++ks)
        wf[ks] = *(const short8v*)(w2 + (size_t)(t * 4 + ks) * 512 + lane * 8);
      float4v y0 = (float4v){0.f, 0.f, 0.f, 0.f};
      float4v y1 = (float4v){0.f, 0.f, 0.f, 0.f};
#pragma unroll
      for (int ks = 0; ks < 4; ++ks) {
        y0 = __builtin_amdgcn_mfma_f32_16x16x32_bf16(wf[ks], a4[0][ks], y0, 0, 0, 0);
        y1 = __builtin_amdgcn_mfma_f32_16x16x32_bf16(wf[ks], a4[1][ks], y1, 0, 0, 0);
      }
      float4 bb = *(const float4*)(b2 + e * D + t * 16 + grp * 4);
      short4v p0, p1;
      p0[0] = f2bf(y0[0] + bb.x);
      p0[1] = f2bf(y0[1] + bb.y);
      p0[2] = f2bf(y0[2] + bb.z);
      p0[3] = f2bf(y0[3] + bb.w);
      p1[0] = f2bf(y1[0] + bb.x);
      p1[1] = f2bf(y1[1] + bb.y);
      p1[2] = f2bf(y1[2] + bb.z);
      p1[3] = f2bf(y1[3] + bb.w);
      *(short4v*)(yrow0 + t * 16 + grp * 4) = p0;
      *(short4v*)(yrow1 + t * 16 + grp * 4) = p1;
    }
  }
}

// ---------------- K6: combine — out[token] = sum of kept slots (or 0) ----------------
__global__ void k_combine(const short* __restrict__ yscr, const int2* __restrict__ tokSlot,
                          float* __restrict__ out) {
  const int idx = blockIdx.x * 256 + threadIdx.x;
  const int token = idx >> 7;
  const int c4 = idx & 127;
  int2 sl = tokSlot[token];
  float4 r = make_float4(0.f, 0.f, 0.f, 0.f);
  if (sl.x >= 0) {
    short4v y = *(const short4v*)(yscr + (size_t)sl.x * D + c4 * 4);
    r.x += bf2f(y[0]); r.y += bf2f(y[1]); r.z += bf2f(y[2]); r.w += bf2f(y[3]);
  }
  if (sl.y >= 0) {
    short4v y = *(const short4v*)(yscr + (size_t)sl.y * D + c4 * 4);
    r.x += bf2f(y[0]); r.y += bf2f(y[1]); r.z += bf2f(y[2]); r.w += bf2f(y[3]);
  }
  reinterpret_cast<float4*>(out)[idx] = r;
}

extern "C" void kernel_launch(void* const* d_in, const int* in_sizes, int n_in,
                              void* d_out, int out_size, void* d_ws, size_t ws_size,
                              hipStream_t stream) {
  const float* x  = (const float*)d_in[0];
  const float* Wr = (const float*)d_in[1];
  const float* br = (const float*)d_in[2];
  const float* W1 = (const float*)d_in[3];
  const float* b1 = (const float*)d_in[4];
  const float* W2 = (const float*)d_in[5];
  const float* b2 = (const float*)d_in[6];
  float* out = (float*)d_out;

  const int N = in_sizes[0] / D;                 // 32768
  const int cap = (int)(1.25f * (float)(N / E)); // 5120
  const int chunks = N / 256;                    // 128
  const int rblocks = N / (4 * RT);              // 1024 router blocks

  int* tokE = (int*)d_ws;                                    // N*2
  float* confPart = (float*)(tokE + (size_t)N * 2);          // rblocks
  int* chunkCnt = (int*)(confPart + rblocks);                // chunks*E
  int* chunkOff = chunkCnt + chunks * E;                     // chunks*E
  int* kept = chunkOff + chunks * E;                         // E
  int2* tokSlot = (int2*)(kept + E);                         // N int2
  int* expList = (int*)(tokSlot + N);                        // E*cap
  short* W1f = (short*)(expList + (size_t)E * cap);          // [E][128][64][8]
  short* W2f = W1f + (size_t)E * H * D;                      // [E][128][64][8]
  short* yscr = W2f + (size_t)E * H * D;                     // [E*cap][D] bf16
  short* xb = yscr + (size_t)E * cap * D;                    // [N][D] bf16 (optional)

  const size_t needed = (size_t)((char*)(xb + (size_t)N * D) - (char*)d_ws);
  const bool useXB = ws_size >= needed;

  k_swizzle<<<dim3(32, E), 256, 0, stream>>>(W1, W2, W1f, W2f);

  k_router<<<rblocks, 256, 0, stream>>>(x, Wr, br, tokE, confPart,
                                        useXB ? xb : nullptr);
  k_count<<<chunks, 256, 0, stream>>>(tokE, chunkCnt);
  k_scan<<<1, 512, 0, stream>>>(chunkCnt, confPart, chunkOff, kept,
                                out + (size_t)N * D, rblocks, cap, N);
  k_dispatch<<<chunks, 256, 0, stream>>>(tokE, chunkOff, expList, tokSlot, cap);

  const int tiles = (cap + BM - 1) / BM;        // 40
  dim3 g5(E, tiles);                            // linear bid % 8 == e -> XCD pin
  if (useXB)
    k_expert_mfma<true><<<g5, 512, 0, stream>>>(xb, x, W1f, b1, W2f, b2,
                                                expList, kept, yscr, cap);
  else
    k_expert_mfma<false><<<g5, 512, 0, stream>>>(nullptr, x, W1f, b1, W2f, b2,
                                                 expList, kept, yscr, cap);

  k_combine<<<(N * D / 4) / 256, 256, 0, stream>>>(yscr, tokSlot, out);
}

// Round 20
// 94.717 us; speedup vs baseline: 1.3315x; 1.1139x over previous
//
#include <hip/hip_runtime.h>

#define D 512
#define E 8
#define H 128
#define BM 160   // tokens per expert block -> 32 tiles/expert -> 256 blocks = 1/CU
#define HP 136   // LDS row stride in shorts (272B)
#define RT 8     // tokens per wave in router

typedef __attribute__((ext_vector_type(8))) short short8v;
typedef __attribute__((ext_vector_type(4))) short short4v;
typedef __attribute__((ext_vector_type(4))) float float4v;

__device__ inline short f2bf(float f) {
  union { float f; unsigned u; } v; v.f = f;
  unsigned r = v.u + 0x7fffu + ((v.u >> 16) & 1u);   // RNE
  return (short)(r >> 16);
}
__device__ inline float bf2f(short s) {
  union { unsigned u; float f; } v;
  v.u = ((unsigned)(unsigned short)s) << 16;
  return v.f;
}
__device__ inline void gload_lds4(const void* g, void* l) {
  __builtin_amdgcn_global_load_lds(
      (const __attribute__((address_space(1))) unsigned int*)g,
      (__attribute__((address_space(3))) unsigned int*)l, 4, 0, 0);
}

// ---------------- K0: swizzle weights into MFMA fragment-contiguous bf16 ----------------
// W1f[e][f=ks*8+t][lane][j]  (ks 0..15, t 0..7)
// W2f[e][f=t*4+ks][lane][j]  (t 0..31,  ks 0..3)   <- t-major
__global__ void k_swizzle(const float* __restrict__ W1, const float* __restrict__ W2,
                          short* __restrict__ W1f, short* __restrict__ W2f) {
  const int e = blockIdx.y;
  const int lane = threadIdx.x & 63;
  const int wv = threadIdx.x >> 6;
  const int r = lane & 15, g = lane >> 4;
  const int which = blockIdx.x >> 4;                 // 0: W1, 1: W2
  const int fbase = ((blockIdx.x & 15) * 4 + wv) * 2;
  if (which == 0) {
#pragma unroll
    for (int f = fbase; f < fbase + 2; ++f) {
      int ks = f >> 3, t = f & 7;
      const float* src = W1 + ((size_t)e * D + ks * 32 + g * 8) * H + t * 16 + r;
      short8v o;
#pragma unroll
      for (int j = 0; j < 8; ++j) o[j] = f2bf(src[(size_t)j * H]);
      *(short8v*)(W1f + (((size_t)e * 128 + f) * 64 + lane) * 8) = o;
    }
  } else {
#pragma unroll
    for (int f = fbase; f < fbase + 2; ++f) {
      int t = f >> 2, ks = f & 3;
      const float* src = W2 + ((size_t)e * H + ks * 32 + g * 8) * D + t * 16 + r;
      short8v o;
#pragma unroll
      for (int j = 0; j < 8; ++j) o[j] = f2bf(src[(size_t)j * D]);
      *(short8v*)(W2f + (((size_t)e * 128 + f) * 64 + lane) * 8) = o;
    }
  }
}

// ---------------- K1: router — one wave per RT tokens, fold-butterfly reduce (fp32 exact) ----------------
__global__ void k_router(const float* __restrict__ x, const float* __restrict__ Wr,
                         const float* __restrict__ br, int* __restrict__ tokE,
                         float* __restrict__ confPart, short* __restrict__ xb) {
  const int lane = threadIdx.x & 63;
  const int wave = threadIdx.x >> 6;
  const int tbase = (blockIdx.x * 4 + wave) * RT;

  float wr[8][8];
  const float4* wrp = reinterpret_cast<const float4*>(Wr) + lane * 16;
#pragma unroll
  for (int j = 0; j < 8; ++j) {
    float4 a = wrp[j * 2 + 0];
    float4 b = wrp[j * 2 + 1];
    wr[j][0] = a.x; wr[j][1] = a.y; wr[j][2] = a.z; wr[j][3] = a.w;
    wr[j][4] = b.x; wr[j][5] = b.y; wr[j][6] = b.z; wr[j][7] = b.w;
  }

  const int myE = ((lane & 1) << 2) | (lane & 2) | ((lane >> 2) & 1);
  const float brv = br[myE];

  float conf = 0.f;

#pragma unroll 2
  for (int tt = 0; tt < RT; ++tt) {
    const int token = tbase + tt;
    const float4* xp = reinterpret_cast<const float4*>(x + (size_t)token * D + lane * 8);
    float4 x0 = xp[0], x1 = xp[1];
    float xv[8] = {x0.x, x0.y, x0.z, x0.w, x1.x, x1.y, x1.z, x1.w};

    if (xb) {
      short8v p;
#pragma unroll
      for (int j = 0; j < 8; ++j) p[j] = f2bf(xv[j]);
      *(short8v*)(xb + (size_t)token * D + lane * 8) = p;
    }

    float v[8] = {0, 0, 0, 0, 0, 0, 0, 0};
#pragma unroll
    for (int j = 0; j < 8; ++j)
#pragma unroll
      for (int e = 0; e < E; ++e)
        v[e] += xv[j] * wr[j][e];

#pragma unroll
    for (int i = 0; i < 4; ++i) {
      float a = v[i] + __shfl_xor(v[i], 1, 64);
      float b = v[i + 4] + __shfl_xor(v[i + 4], 1, 64);
      v[i] = (lane & 1) ? b : a;
    }
#pragma unroll
    for (int i = 0; i < 2; ++i) {
      float a = v[i] + __shfl_xor(v[i], 2, 64);
      float b = v[i + 2] + __shfl_xor(v[i + 2], 2, 64);
      v[i] = (lane & 2) ? b : a;
    }
    {
      float a = v[0] + __shfl_xor(v[0], 4, 64);
      float b = v[1] + __shfl_xor(v[1], 4, 64);
      v[0] = (lane & 4) ? b : a;
    }
    v[0] += __shfl_xor(v[0], 8, 64);
    v[0] += __shfl_xor(v[0], 16, 64);
    v[0] += __shfl_xor(v[0], 32, 64);

    const float logit = v[0] + brv;

    float m1 = logit; int i1 = myE;
#pragma unroll
    for (int m = 1; m <= 4; m <<= 1) {
      float om = __shfl_xor(m1, m, 64);
      int oi = __shfl_xor(i1, m, 64);
      bool take = (om > m1) || (om == m1 && oi < i1);
      m1 = take ? om : m1;
      i1 = take ? oi : i1;
    }
    float s1 = (myE == i1) ? -1e30f : logit; int j1 = myE;
#pragma unroll
    for (int m = 1; m <= 4; m <<= 1) {
      float om = __shfl_xor(s1, m, 64);
      int oi = __shfl_xor(j1, m, 64);
      bool take = (om > s1) || (om == s1 && oi < j1);
      s1 = take ? om : s1;
      j1 = take ? oi : j1;
    }

    if (lane == 0) {
      tokE[token * 2 + 0] = i1;
      tokE[token * 2 + 1] = j1;
    }
    conf += m1;
  }

  __shared__ float cf[4];
  if (lane == 0) cf[wave] = conf;
  __syncthreads();
  if (threadIdx.x == 0) confPart[blockIdx.x] = cf[0] + cf[1] + cf[2] + cf[3];
}

// ---------------- K2: per-chunk (256 tokens) expert counts ----------------
__global__ void k_count(const int* __restrict__ tokE, int* __restrict__ chunkCnt) {
  __shared__ int c[E];
  if (threadIdx.x < E) c[threadIdx.x] = 0;
  __syncthreads();
  int token = blockIdx.x * 256 + threadIdx.x;
  atomicAdd(&c[tokE[token * 2 + 0]], 1);
  atomicAdd(&c[tokE[token * 2 + 1]], 1);
  __syncthreads();
  if (threadIdx.x < E) chunkCnt[blockIdx.x * E + threadIdx.x] = c[threadIdx.x];
}

// ---------------- K3: wave-parallel scan + stats ----------------
__global__ void k_scan(const int* __restrict__ chunkCnt, const float* __restrict__ confPart,
                       int* __restrict__ chunkOff, int* __restrict__ kept,
                       float* __restrict__ outTail, int nConf, int cap, int nTok) {
  const int lane = threadIdx.x & 63;
  const int e = threadIdx.x >> 6;
  __shared__ int keptS[E];

  int v0 = chunkCnt[lane * E + e];
  int v1 = chunkCnt[(64 + lane) * E + e];
  int s0 = v0, s1 = v1;
#pragma unroll
  for (int off = 1; off < 64; off <<= 1) {
    int t0 = __shfl_up(s0, off, 64);
    int t1 = __shfl_up(s1, off, 64);
    if (lane >= off) { s0 += t0; s1 += t1; }
  }
  int tot0 = __shfl(s0, 63, 64);
  int total = tot0 + __shfl(s1, 63, 64);
  chunkOff[lane * E + e] = s0 - v0;
  chunkOff[(64 + lane) * E + e] = tot0 + s1 - v1;
  if (lane == 0) {
    int k = min(total, cap);
    kept[e] = k;
    keptS[e] = k;
  }

  __shared__ float s[512];
  float a = 0.f;
  for (int i = threadIdx.x; i < nConf; i += 512) a += confPart[i];
  s[threadIdx.x] = a;
  __syncthreads();
  for (int st = 256; st > 0; st >>= 1) {
    if (threadIdx.x < st) s[threadIdx.x] += s[threadIdx.x + st];
    __syncthreads();
  }
  if (threadIdx.x == 0) {
    float tot = 0.f, ld[E];
    for (int i = 0; i < E; ++i) { ld[i] = (float)keptS[i]; tot += ld[i]; }
    float denom = tot + 1e-8f;
    float loss = 0.f;
    for (int i = 0; i < E; ++i) {
      float dist = ld[i] / denom;
      loss += dist * logf(dist + 1e-8f);
      outTail[1 + i] = dist;
    }
    outTail[0] = loss;
    outTail[1 + E] = s[0] / (float)nTok;
  }
}

// ---------------- K4: rank assignment + dispatch lists + token->slot map ----------------
__global__ void k_dispatch(const int* __restrict__ tokE, const int* __restrict__ chunkOff,
                           int* __restrict__ expList, int2* __restrict__ tokSlot, int cap) {
  const int lane = threadIdx.x & 63;
  const int wave = threadIdx.x >> 6;
  const int token = blockIdx.x * 256 + threadIdx.x;
  const int e0 = tokE[token * 2 + 0];
  const int e1 = tokE[token * 2 + 1];
  __shared__ int wcnt[4][E];
  unsigned long long lt = (lane == 63) ? 0x7fffffffffffffffull : ((1ull << lane) - 1ull);
  int r0 = 0, r1 = 0;
#pragma unroll
  for (int e = 0; e < E; ++e) {
    unsigned long long b0 = __ballot(e0 == e);
    unsigned long long b1 = __ballot(e1 == e);
    unsigned long long m = b0 | b1;
    if (e0 == e) r0 = __popcll(m & lt);
    if (e1 == e) r1 = __popcll(m & lt);
    if (lane == 0) wcnt[wave][e] = __popcll(m);
  }
  __syncthreads();
  int base0 = chunkOff[blockIdx.x * E + e0];
  int base1 = chunkOff[blockIdx.x * E + e1];
  for (int w = 0; w < wave; ++w) {
    base0 += wcnt[w][e0];
    base1 += wcnt[w][e1];
  }
  int g0 = base0 + r0;
  int g1 = base1 + r1;
  if (g0 < cap) expList[e0 * cap + g0] = token;
  if (g1 < cap) expList[e1 * cap + g1] = token;
  tokSlot[token] = make_int2(g0 < cap ? e0 * cap + g0 : -1,
                             g1 < cap ? e1 * cap + g1 : -1);
}

// ---------------- K5: per-expert FFN via MFMA, 160 tokens/block, 256 blocks = 1/CU ----------------
// 8 waves = (rowg 0..1) x (ng 0..3). rowg half = 80 rows = 5 row-tiles.
// L1: each W1 frag feeds 5 MFMAs. L2: fused pass, each W2 frag feeds 5 MFMAs.
template <bool USE_XB>
__global__ __launch_bounds__(512, 1) void k_expert_mfma(
    const short* __restrict__ xb, const float* __restrict__ x,
    const short* __restrict__ W1f, const float* __restrict__ b1,
    const short* __restrict__ W2f, const float* __restrict__ b2,
    const int* __restrict__ expList, const int* __restrict__ kept,
    short* __restrict__ yscr, int cap) {
  const int e = blockIdx.x;                 // linear bid % 8 == e -> XCD pin
  const int cnt = kept[e];
  const int t0 = blockIdx.y * BM;
  if (t0 >= cnt) return;
  const int lane = threadIdx.x & 63;
  const int wave = threadIdx.x >> 6;   // 0..7
  const int rowg = wave >> 2;          // 0..1 -> rows [rowg*80, rowg*80+80)
  const int ng = wave & 3;             // 0..3 -> output-column quarter
  const int n15 = lane & 15;
  const int grp = lane >> 4;
  const int kg = grp * 8;

  __shared__ int toks[BM];
  __shared__ short sbuf[2 * BM * HP];   // x phase double-buffer; buf0 reused as hs

  if (threadIdx.x < BM) {
    int idx = min(t0 + (int)threadIdx.x, cnt - 1);
    toks[threadIdx.x] = expList[e * cap + idx];
  }
  __syncthreads();

  const short* w1 = W1f + (size_t)e * (128 * 512);
  const short* w2 = W2f + (size_t)e * (128 * 512);

  float4v acc[5][2];
#pragma unroll
  for (int r = 0; r < 5; ++r)
#pragma unroll
    for (int t = 0; t < 2; ++t)
      acc[r][t] = (float4v){0.f, 0.f, 0.f, 0.f};

  if (USE_XB) {
    // stage phase p: token row bytes [p*256, +256) -> sbuf[p&1][ti][..]; 20 rows/wave
    auto stageX = [&](int p) {
#pragma unroll
      for (int j = 0; j < 20; ++j) {
        int ti = wave * 20 + j;
        const short* src = xb + (size_t)toks[ti] * D + p * 128 + lane * 2;
        short* dst = &sbuf[(p & 1) * (BM * HP) + ti * HP];
        gload_lds4(src, dst);
      }
    };
    stageX(0);
    __syncthreads();
#pragma unroll
    for (int p = 0; p < 4; ++p) {
      if (p < 3) stageX(p + 1);
#pragma unroll
      for (int ksl = 0; ksl < 4; ++ksl) {
        const int ks = p * 4 + ksl;
        const short* sb = &sbuf[(p & 1) * (BM * HP)];
        short8v xf[5];
#pragma unroll
        for (int r = 0; r < 5; ++r)
          xf[r] = *(const short8v*)&sb[(rowg * 80 + r * 16 + n15) * HP + ksl * 32 + kg];
        short8v wf[2];
#pragma unroll
        for (int t = 0; t < 2; ++t)
          wf[t] = *(const short8v*)(w1 + (size_t)(ks * 8 + ng * 2 + t) * 512 + lane * 8);
#pragma unroll
        for (int t = 0; t < 2; ++t)
#pragma unroll
          for (int r = 0; r < 5; ++r)
            acc[r][t] = __builtin_amdgcn_mfma_f32_16x16x32_bf16(wf[t], xf[r], acc[r][t], 0, 0, 0);
      }
      __syncthreads();
    }
  } else {
    // fallback: per-lane gather from fp32 x (correctness path)
#pragma unroll 1
    for (int ks = 0; ks < 16; ++ks) {
      short8v xf[5];
#pragma unroll
      for (int r = 0; r < 5; ++r) {
        const float* xr = x + (size_t)toks[rowg * 80 + r * 16 + n15] * D + kg + ks * 32;
        float4 a0 = *(const float4*)(xr);
        float4 a1 = *(const float4*)(xr + 4);
        short8v f;
        f[0] = f2bf(a0.x); f[1] = f2bf(a0.y); f[2] = f2bf(a0.z); f[3] = f2bf(a0.w);
        f[4] = f2bf(a1.x); f[5] = f2bf(a1.y); f[6] = f2bf(a1.z); f[7] = f2bf(a1.w);
        xf[r] = f;
      }
      short8v wf[2];
#pragma unroll
      for (int t = 0; t < 2; ++t)
        wf[t] = *(const short8v*)(w1 + (size_t)(ks * 8 + ng * 2 + t) * 512 + lane * 8);
#pragma unroll
      for (int t = 0; t < 2; ++t)
#pragma unroll
        for (int r = 0; r < 5; ++r)
          acc[r][t] = __builtin_amdgcn_mfma_f32_16x16x32_bf16(wf[t], xf[r], acc[r][t], 0, 0, 0);
    }
    __syncthreads();
  }

  // ---- h = relu(acc + b1) -> sbuf buffer0; wave writes 5 row-tiles x 2 col-tiles ----
#pragma unroll
  for (int t = 0; t < 2; ++t) {
    int tg = ng * 2 + t;
    float4 bb = *(const float4*)(b1 + e * H + tg * 16 + grp * 4);
#pragma unroll
    for (int r = 0; r < 5; ++r) {
      short4v p;
      p[0] = f2bf(fmaxf(acc[r][t][0] + bb.x, 0.f));
      p[1] = f2bf(fmaxf(acc[r][t][1] + bb.y, 0.f));
      p[2] = f2bf(fmaxf(acc[r][t][2] + bb.z, 0.f));
      p[3] = f2bf(fmaxf(acc[r][t][3] + bb.w, 0.f));
      *(short4v*)(&sbuf[(rowg * 80 + r * 16 + n15) * HP + tg * 16 + grp * 4]) = p;
    }
  }
  __syncthreads();

  // ---- layer 2: fused pass — 5 row-tiles x 8 d-tiles (each W2 frag -> 5 MFMAs) ----
  short8v a4[5][4];   // [ri][ks]
#pragma unroll
  for (int ri = 0; ri < 5; ++ri)
#pragma unroll
    for (int ks = 0; ks < 4; ++ks)
      a4[ri][ks] = *(const short8v*)(&sbuf[(rowg * 80 + ri * 16 + n15) * HP + ks * 32 + kg]);

  short* yr0 = yscr + ((size_t)(e * cap + t0 + rowg * 80 + n15)) * D;
#pragma unroll 4
  for (int tt = 0; tt < 8; ++tt) {
    const int t = ng * 8 + tt;
    short8v wf[4];
#pragma unroll
    for (int ks = 0; ks < 4; ++ks)
      wf[ks] = *(const short8v*)(w2 + (size_t)(t * 4 + ks) * 512 + lane * 8);
    float4 bb = *(const float4*)(b2 + e * D + t * 16 + grp * 4);
#pragma unroll
    for (int ri = 0; ri < 5; ++ri) {
      float4v y = (float4v){0.f, 0.f, 0.f, 0.f};
      y = __builtin_amdgcn_mfma_f32_16x16x32_bf16(wf[0], a4[ri][0], y, 0, 0, 0);
      y = __builtin_amdgcn_mfma_f32_16x16x32_bf16(wf[1], a4[ri][1], y, 0, 0, 0);
      y = __builtin_amdgcn_mfma_f32_16x16x32_bf16(wf[2], a4[ri][2], y, 0, 0, 0);
      y = __builtin_amdgcn_mfma_f32_16x16x32_bf16(wf[3], a4[ri][3], y, 0, 0, 0);
      short4v pv;
      pv[0] = f2bf(y[0] + bb.x);
      pv[1] = f2bf(y[1] + bb.y);
      pv[2] = f2bf(y[2] + bb.z);
      pv[3] = f2bf(y[3] + bb.w);
      *(short4v*)(yr0 + (size_t)ri * 16 * D + t * 16 + grp * 4) = pv;
    }
  }
}

// ---------------- K6: combine — out[token] = sum of kept slots (or 0) ----------------
__global__ void k_combine(const short* __restrict__ yscr, const int2* __restrict__ tokSlot,
                          float* __restrict__ out) {
  const int idx = blockIdx.x * 256 + threadIdx.x;
  const int token = idx >> 7;
  const int c4 = idx & 127;
  int2 sl = tokSlot[token];
  float4 r = make_float4(0.f, 0.f, 0.f, 0.f);
  if (sl.x >= 0) {
    short4v y = *(const short4v*)(yscr + (size_t)sl.x * D + c4 * 4);
    r.x += bf2f(y[0]); r.y += bf2f(y[1]); r.z += bf2f(y[2]); r.w += bf2f(y[3]);
  }
  if (sl.y >= 0) {
    short4v y = *(const short4v*)(yscr + (size_t)sl.y * D + c4 * 4);
    r.x += bf2f(y[0]); r.y += bf2f(y[1]); r.z += bf2f(y[2]); r.w += bf2f(y[3]);
  }
  reinterpret_cast<float4*>(out)[idx] = r;
}

extern "C" void kernel_launch(void* const* d_in, const int* in_sizes, int n_in,
                              void* d_out, int out_size, void* d_ws, size_t ws_size,
                              hipStream_t stream) {
  const float* x  = (const float*)d_in[0];
  const float* Wr = (const float*)d_in[1];
  const float* br = (const float*)d_in[2];
  const float* W1 = (const float*)d_in[3];
  const float* b1 = (const float*)d_in[4];
  const float* W2 = (const float*)d_in[5];
  const float* b2 = (const float*)d_in[6];
  float* out = (float*)d_out;

  const int N = in_sizes[0] / D;                 // 32768
  const int cap = (int)(1.25f * (float)(N / E)); // 5120
  const int chunks = N / 256;                    // 128
  const int rblocks = N / (4 * RT);              // 1024 router blocks

  int* tokE = (int*)d_ws;                                    // N*2
  float* confPart = (float*)(tokE + (size_t)N * 2);          // rblocks
  int* chunkCnt = (int*)(confPart + rblocks);                // chunks*E
  int* chunkOff = chunkCnt + chunks * E;                     // chunks*E
  int* kept = chunkOff + chunks * E;                         // E
  int2* tokSlot = (int2*)(kept + E);                         // N int2
  int* expList = (int*)(tokSlot + N);                        // E*cap
  short* W1f = (short*)(expList + (size_t)E * cap);          // [E][128][64][8]
  short* W2f = W1f + (size_t)E * H * D;                      // [E][128][64][8]
  short* yscr = W2f + (size_t)E * H * D;                     // [E*cap][D] bf16
  short* xb = yscr + (size_t)E * cap * D;                    // [N][D] bf16 (optional)

  const size_t needed = (size_t)((char*)(xb + (size_t)N * D) - (char*)d_ws);
  const bool useXB = ws_size >= needed;

  k_swizzle<<<dim3(32, E), 256, 0, stream>>>(W1, W2, W1f, W2f);

  k_router<<<rblocks, 256, 0, stream>>>(x, Wr, br, tokE, confPart,
                                        useXB ? xb : nullptr);
  k_count<<<chunks, 256, 0, stream>>>(tokE, chunkCnt);
  k_scan<<<1, 512, 0, stream>>>(chunkCnt, confPart, chunkOff, kept,
                                out + (size_t)N * D, rblocks, cap, N);
  k_dispatch<<<chunks, 256, 0, stream>>>(tokE, chunkOff, expList, tokSlot, cap);

  const int tiles = (cap + BM - 1) / BM;        // 32
  dim3 g5(E, tiles);                            // 256 blocks = exactly 1 per CU
  if (useXB)
    k_expert_mfma<true><<<g5, 512, 0, stream>>>(xb, x, W1f, b1, W2f, b2,
                                                expList, kept, yscr, cap);
  else
    k_expert_mfma<false><<<g5, 512, 0, stream>>>(nullptr, x, W1f, b1, W2f, b2,
                                                 expList, kept, yscr, cap);

  k_combine<<<(N * D / 4) / 256, 256, 0, stream>>>(yscr, tokSlot, out);
}